// Round 2
// baseline (462.232 us; speedup 1.0000x reference)
//
#include <hip/hip_runtime.h>
#include <math.h>

#define P_ 32
#define G_ 256
#define NV 6890
#define M_ (2 * NV)          // 13780 joint points per sample
#define NPAIR (P_ * G_)      // 8192
#define NC 8                 // K-split chunks per pair-tile
#define CV 128               // vertices staged per LDS chunk
#define RS 516               // LDS row stride in dwords (CV*4 + 4 -> bank-balanced)

// ---------------- workspace layout ----------------
struct WS {
    float mu_p[P_][3];
    float var_p[P_];
    float mu_g[G_][3];
    float At[NPAIR][12];          // A = scale*R (9) then t (3); pair = g*32 + p
    float partK[NC][NPAIR][9];    // per-chunk partial cross-covariance
    float partE[NC][NPAIR];       // per-chunk partial sum of v2v norms
};

// ---------------- block reduction (valid on thread 0) ----------------
__device__ inline double block_reduce(double v, double* smem) {
#pragma unroll
    for (int off = 32; off > 0; off >>= 1) v += __shfl_down(v, off, 64);
    int wid  = threadIdx.x >> 6;
    int lane = threadIdx.x & 63;
    __syncthreads();
    if (lane == 0) smem[wid] = v;
    __syncthreads();
    double r = 0.0;
    if (threadIdx.x == 0) {
        int nw = blockDim.x >> 6;
        for (int w = 0; w < nw; ++w) r += smem[w];
    }
    return r;
}

// ---------------- kernel 1: pred stats (mu_p, var_p) ----------------
__global__ __launch_bounds__(256) void pred_stats(const float* __restrict__ pred, WS* ws) {
    int p = blockIdx.x;
    const float* base = pred + (size_t)p * M_ * 3;
    double sx = 0, sy = 0, sz = 0, sq = 0;
    for (int i = threadIdx.x; i < M_; i += 256) {
        float x = base[3 * i + 0];
        float y = base[3 * i + 1];
        float z = base[3 * i + 2];
        sx += x; sy += y; sz += z;
        sq += (double)x * x + (double)y * y + (double)z * z;
    }
    __shared__ double smem[4];
    double rx = block_reduce(sx, smem);
    double ry = block_reduce(sy, smem);
    double rz = block_reduce(sz, smem);
    double rq = block_reduce(sq, smem);
    if (threadIdx.x == 0) {
        double mx = rx / M_, my = ry / M_, mz = rz / M_;
        ws->mu_p[p][0] = (float)mx;
        ws->mu_p[p][1] = (float)my;
        ws->mu_p[p][2] = (float)mz;
        ws->var_p[p] = (float)(rq - (mx * mx + my * my + mz * mz) * (double)M_);
    }
}

// ---------------- kernel 2: gt stats (mu_g) ----------------
__global__ __launch_bounds__(256) void gt_stats(const float* __restrict__ gt, WS* ws) {
    int g = blockIdx.x;
    const float* base = gt + (size_t)g * M_ * 3;
    double sx = 0, sy = 0, sz = 0;
    for (int i = threadIdx.x; i < M_; i += 256) {
        sx += base[3 * i + 0];
        sy += base[3 * i + 1];
        sz += base[3 * i + 2];
    }
    __shared__ double smem[4];
    double rx = block_reduce(sx, smem);
    double ry = block_reduce(sy, smem);
    double rz = block_reduce(sz, smem);
    if (threadIdx.x == 0) {
        ws->mu_g[g][0] = (float)(rx / M_);
        ws->mu_g[g][1] = (float)(ry / M_);
        ws->mu_g[g][2] = (float)(rz / M_);
    }
}

// ---------------- staging helper: 16 sample-chunks -> LDS (float4-padded) ----------------
// lds rows: 0..7 = pred samples pbase..pbase+7, 8..15 = gt samples gbase..gbase+7
__device__ inline void stage_chunk(const float* __restrict__ src, int vb, int nv,
                                   float* __restrict__ lds, int t) {
    int s = t & 15;
    for (int j = t >> 4; j < nv; j += 16) {
        const float* v3 = src + 3 * (size_t)(vb + j);
        float4 val;
        val.x = v3[0]; val.y = v3[1]; val.z = v3[2]; val.w = 0.f;
        *(float4*)&lds[s * RS + 4 * j] = val;
    }
}

// ---------------- kernel 3: tiled cross-covariance partials ----------------
// grid: bx -> ptile (4) x gtile (32) x kchunk (NC)
__global__ __launch_bounds__(256) void crosscov_t(const float* __restrict__ pred,
                                                  const float* __restrict__ gt,
                                                  WS* __restrict__ ws) {
    __shared__ float lds[16 * RS];   // 33 KB
    int bx = blockIdx.x;
    int pt = bx & 3;
    int gtile = (bx >> 2) & 31;
    int kc = bx >> 7;
    int pbase = pt * 8, gbase = gtile * 8;
    int vbeg = (int)(((long long)M_ * kc) / NC);
    int vend = (int)(((long long)M_ * (kc + 1)) / NC);

    int t = threadIdx.x;
    int s = t & 15;
    const float* src = (s < 8) ? pred + (size_t)(pbase + s) * (M_ * 3)
                               : gt   + (size_t)(gbase + s - 8) * (M_ * 3);
    int pp = t & 7, w = t >> 3;   // w in 0..31: vertex phase

    float acc[8][9];
#pragma unroll
    for (int g = 0; g < 8; ++g)
#pragma unroll
        for (int j = 0; j < 9; ++j) acc[g][j] = 0.f;

    for (int vb = vbeg; vb < vend; vb += CV) {
        int nv = vend - vb; if (nv > CV) nv = CV;
        __syncthreads();
        stage_chunk(src, vb, nv, lds, t);
        __syncthreads();
        for (int v = w; v < nv; v += 32) {
            float4 x = *(const float4*)&lds[pp * RS + 4 * v];
#pragma unroll
            for (int gg = 0; gg < 8; ++gg) {
                float4 y = *(const float4*)&lds[(8 + gg) * RS + 4 * v];
                acc[gg][0] = fmaf(x.x, y.x, acc[gg][0]);
                acc[gg][1] = fmaf(x.x, y.y, acc[gg][1]);
                acc[gg][2] = fmaf(x.x, y.z, acc[gg][2]);
                acc[gg][3] = fmaf(x.y, y.x, acc[gg][3]);
                acc[gg][4] = fmaf(x.y, y.y, acc[gg][4]);
                acc[gg][5] = fmaf(x.y, y.z, acc[gg][5]);
                acc[gg][6] = fmaf(x.z, y.x, acc[gg][6]);
                acc[gg][7] = fmaf(x.z, y.y, acc[gg][7]);
                acc[gg][8] = fmaf(x.z, y.z, acc[gg][8]);
            }
        }
    }
    // reduce across the 8 vertex-phase lanes within the wave (xor 8,16,32)
#pragma unroll
    for (int g = 0; g < 8; ++g)
#pragma unroll
        for (int j = 0; j < 9; ++j) {
            float v = acc[g][j];
            v += __shfl_xor(v, 8);
            v += __shfl_xor(v, 16);
            v += __shfl_xor(v, 32);
            acc[g][j] = v;
        }
    __syncthreads();
    int lane = t & 63, wave = t >> 6;
    if (lane < 8) {
#pragma unroll
        for (int g = 0; g < 8; ++g)
#pragma unroll
            for (int j = 0; j < 9; ++j)
                lds[wave * 576 + lane * 72 + g * 9 + j] = acc[g][j];
    }
    __syncthreads();
    for (int o = t; o < 576; o += 256) {
        int ppo = o / 72, rem = o % 72;
        int ggo = rem / 9, jo = rem % 9;
        float sum = lds[o] + lds[576 + o] + lds[2 * 576 + o] + lds[3 * 576 + o];
        int pair = (gbase + ggo) * P_ + (pbase + ppo);
        ws->partK[kc][pair][jo] = sum;
    }
}

// ---------------- kernel 4: per-pair SVD -> A = scale*R, t ----------------
__global__ __launch_bounds__(256) void pair_svd(WS* ws) {
    int pair = blockIdx.x * blockDim.x + threadIdx.x;
    if (pair >= NPAIR) return;
    int p = pair & 31;
    int g = pair >> 5;

    double K[3][3];
#pragma unroll
    for (int a = 0; a < 3; ++a)
#pragma unroll
        for (int b = 0; b < 3; ++b) {
            double sacc = 0.0;
            for (int kc = 0; kc < NC; ++kc) sacc += (double)ws->partK[kc][pair][3 * a + b];
            K[a][b] = sacc;
        }
    {   // subtract M * mu_p mu_g^T
        double mp[3] = { ws->mu_p[p][0], ws->mu_p[p][1], ws->mu_p[p][2] };
        double mg[3] = { ws->mu_g[g][0], ws->mu_g[g][1], ws->mu_g[g][2] };
#pragma unroll
        for (int a = 0; a < 3; ++a)
#pragma unroll
            for (int b = 0; b < 3; ++b)
                K[a][b] -= (double)M_ * mp[a] * mg[b];
    }

    // S = K^T K (symmetric PSD)
    double S[3][3];
#pragma unroll
    for (int a = 0; a < 3; ++a)
#pragma unroll
        for (int b = 0; b < 3; ++b) {
            double acc = 0.0;
#pragma unroll
            for (int c = 0; c < 3; ++c) acc += K[c][a] * K[c][b];
            S[a][b] = acc;
        }

    // Jacobi eigendecomposition S = V Lambda V^T
    double V[3][3] = { {1, 0, 0}, {0, 1, 0}, {0, 0, 1} };
    double tr = S[0][0] + S[1][1] + S[2][2];
    double tol = 1e-30 * tr * tr + 1e-300;
    const int PP[3] = {0, 0, 1};
    const int QQ[3] = {1, 2, 2};
    for (int sweep = 0; sweep < 30; ++sweep) {
        double off = S[0][1] * S[0][1] + S[0][2] * S[0][2] + S[1][2] * S[1][2];
        if (off <= tol) break;
        for (int r3 = 0; r3 < 3; ++r3) {
            int pq = PP[r3], qq = QQ[r3];
            double apq = S[pq][qq];
            if (apq == 0.0) continue;
            double theta = (S[qq][qq] - S[pq][pq]) / (2.0 * apq);
            double tt = copysign(1.0, theta) / (fabs(theta) + sqrt(theta * theta + 1.0));
            double c = 1.0 / sqrt(tt * tt + 1.0);
            double sj = tt * c;
            for (int r = 0; r < 3; ++r) {
                double srp = S[r][pq], srq = S[r][qq];
                S[r][pq] = c * srp - sj * srq;
                S[r][qq] = sj * srp + c * srq;
            }
            for (int cc = 0; cc < 3; ++cc) {
                double spr = S[pq][cc], sqr = S[qq][cc];
                S[pq][cc] = c * spr - sj * sqr;
                S[qq][cc] = sj * spr + c * sqr;
            }
            for (int r = 0; r < 3; ++r) {
                double vrp = V[r][pq], vrq = V[r][qq];
                V[r][pq] = c * vrp - sj * vrq;
                V[r][qq] = sj * vrp + c * vrq;
            }
        }
    }

    // sort eigenpairs descending
    double lam[3] = { S[0][0], S[1][1], S[2][2] };
    int idx[3] = { 0, 1, 2 };
    if (lam[idx[0]] < lam[idx[1]]) { int tt = idx[0]; idx[0] = idx[1]; idx[1] = tt; }
    if (lam[idx[0]] < lam[idx[2]]) { int tt = idx[0]; idx[0] = idx[2]; idx[2] = tt; }
    if (lam[idx[1]] < lam[idx[2]]) { int tt = idx[1]; idx[1] = idx[2]; idx[2] = tt; }
    double Vs[3][3];
    double sv[3];
#pragma unroll
    for (int i = 0; i < 3; ++i) {
        double l = lam[idx[i]];
        sv[i] = sqrt(l > 0.0 ? l : 0.0);
        for (int r = 0; r < 3; ++r) Vs[r][i] = V[r][idx[i]];
    }

    // U columns: u_i = K v_i / s_i
    double U[3][3];
#pragma unroll
    for (int i = 0; i < 3; ++i) {
        double kx = K[0][0] * Vs[0][i] + K[0][1] * Vs[1][i] + K[0][2] * Vs[2][i];
        double ky = K[1][0] * Vs[0][i] + K[1][1] * Vs[1][i] + K[1][2] * Vs[2][i];
        double kz = K[2][0] * Vs[0][i] + K[2][1] * Vs[1][i] + K[2][2] * Vs[2][i];
        double inv = (sv[i] > 1e-12 * sv[0] && sv[i] > 0.0) ? 1.0 / sv[i] : 0.0;
        U[0][i] = kx * inv; U[1][i] = ky * inv; U[2][i] = kz * inv;
    }
    if (sv[2] <= 1e-12 * sv[0] || sv[0] == 0.0) {
        U[0][2] = U[1][0] * U[2][1] - U[2][0] * U[1][1];
        U[1][2] = U[2][0] * U[0][1] - U[0][0] * U[2][1];
        U[2][2] = U[0][0] * U[1][1] - U[1][0] * U[0][1];
    }

    double detK = K[0][0] * (K[1][1] * K[2][2] - K[1][2] * K[2][1])
                - K[0][1] * (K[1][0] * K[2][2] - K[1][2] * K[2][0])
                + K[0][2] * (K[1][0] * K[2][1] - K[1][1] * K[2][0]);
    double d = (detK >= 0.0) ? 1.0 : -1.0;

    double varp = (double)ws->var_p[p];
    double scale = (sv[0] + sv[1] + d * sv[2]) / varp;

    float A[9];
#pragma unroll
    for (int a = 0; a < 3; ++a)
#pragma unroll
        for (int b = 0; b < 3; ++b) {
            double r = Vs[a][0] * U[b][0] + Vs[a][1] * U[b][1] + d * Vs[a][2] * U[b][2];
            A[3 * a + b] = (float)(scale * r);
        }
    double mp[3] = { ws->mu_p[p][0], ws->mu_p[p][1], ws->mu_p[p][2] };
    double mg[3] = { ws->mu_g[g][0], ws->mu_g[g][1], ws->mu_g[g][2] };
    float tvec[3];
#pragma unroll
    for (int a = 0; a < 3; ++a)
        tvec[a] = (float)(mg[a] - ((double)A[3 * a + 0] * mp[0] + (double)A[3 * a + 1] * mp[1] +
                                   (double)A[3 * a + 2] * mp[2]));

#pragma unroll
    for (int j = 0; j < 9; ++j) ws->At[pair][j] = A[j];
#pragma unroll
    for (int j = 0; j < 3; ++j) ws->At[pair][9 + j] = tvec[j];
}

// ---------------- kernel 5: tiled v2v error partials ----------------
__global__ __launch_bounds__(256) void pair_error_t(const float* __restrict__ pred,
                                                    const float* __restrict__ gt,
                                                    WS* __restrict__ ws) {
    __shared__ float lds[16 * RS];
    int bx = blockIdx.x;
    int pt = bx & 3;
    int gtile = (bx >> 2) & 31;
    int kc = bx >> 7;
    int pbase = pt * 8, gbase = gtile * 8;
    int vbeg = (int)(((long long)M_ * kc) / NC);
    int vend = (int)(((long long)M_ * (kc + 1)) / NC);

    int t = threadIdx.x;
    int s = t & 15;
    const float* src = (s < 8) ? pred + (size_t)(pbase + s) * (M_ * 3)
                               : gt   + (size_t)(gbase + s - 8) * (M_ * 3);
    int pp = t & 7, w = t >> 3;

    float A[8][12];
#pragma unroll
    for (int gg = 0; gg < 8; ++gg) {
        int pair = (gbase + gg) * P_ + (pbase + pp);
#pragma unroll
        for (int j = 0; j < 12; ++j) A[gg][j] = ws->At[pair][j];
    }

    float acc[8];
#pragma unroll
    for (int gg = 0; gg < 8; ++gg) acc[gg] = 0.f;

    for (int vb = vbeg; vb < vend; vb += CV) {
        int nv = vend - vb; if (nv > CV) nv = CV;
        __syncthreads();
        stage_chunk(src, vb, nv, lds, t);
        __syncthreads();
        for (int v = w; v < nv; v += 32) {
            float4 x = *(const float4*)&lds[pp * RS + 4 * v];
#pragma unroll
            for (int gg = 0; gg < 8; ++gg) {
                float4 y = *(const float4*)&lds[(8 + gg) * RS + 4 * v];
                float dx = fmaf(A[gg][0], x.x, fmaf(A[gg][1], x.y, fmaf(A[gg][2], x.z, A[gg][9])))  - y.x;
                float dy = fmaf(A[gg][3], x.x, fmaf(A[gg][4], x.y, fmaf(A[gg][5], x.z, A[gg][10]))) - y.y;
                float dz = fmaf(A[gg][6], x.x, fmaf(A[gg][7], x.y, fmaf(A[gg][8], x.z, A[gg][11]))) - y.z;
                acc[gg] += sqrtf(fmaf(dx, dx, fmaf(dy, dy, dz * dz)));
            }
        }
    }
#pragma unroll
    for (int gg = 0; gg < 8; ++gg) {
        float v = acc[gg];
        v += __shfl_xor(v, 8);
        v += __shfl_xor(v, 16);
        v += __shfl_xor(v, 32);
        acc[gg] = v;
    }
    __syncthreads();
    int lane = t & 63, wave = t >> 6;
    if (lane < 8) {
#pragma unroll
        for (int gg = 0; gg < 8; ++gg)
            lds[wave * 64 + lane * 8 + gg] = acc[gg];
    }
    __syncthreads();
    if (t < 64) {
        int ppo = t >> 3, ggo = t & 7;
        float sum = lds[ppo * 8 + ggo] + lds[64 + ppo * 8 + ggo] +
                    lds[128 + ppo * 8 + ggo] + lds[192 + ppo * 8 + ggo];
        int pair = (gbase + ggo) * P_ + (pbase + ppo);
        ws->partE[kc][pair] = sum;
    }
}

// ---------------- kernel 6: argmin over gallery + write outputs ----------------
__global__ void argmin_out(const WS* __restrict__ ws, float* __restrict__ out) {
    int p = threadIdx.x;
    if (p >= P_) return;
    float best = 3.4e38f;
    int bi = 0;
    for (int g = 0; g < G_; ++g) {
        double s = 0.0;
#pragma unroll
        for (int kc = 0; kc < NC; ++kc) s += (double)ws->partE[kc][g * P_ + p];
        float e = (float)(s / (double)M_);
        if (e < best) { best = e; bi = g; }
    }
    out[p] = (float)bi;
    out[P_ + p] = best;
}

extern "C" void kernel_launch(void* const* d_in, const int* in_sizes, int n_in,
                              void* d_out, int out_size, void* d_ws, size_t ws_size,
                              hipStream_t stream) {
    const float* pred = (const float*)d_in[0];   // (32, 2, 6890, 3)
    const float* gt   = (const float*)d_in[1];   // (256, 2, 6890, 3)
    float* out = (float*)d_out;                  // 64 floats: mapping(32) | min_error(32)
    WS* ws = (WS*)d_ws;                          // ~3.1 MB used

    pred_stats<<<dim3(P_), dim3(256), 0, stream>>>(pred, ws);
    gt_stats<<<dim3(G_), dim3(256), 0, stream>>>(gt, ws);
    crosscov_t<<<dim3(4 * 32 * NC), dim3(256), 0, stream>>>(pred, gt, ws);
    pair_svd<<<dim3(NPAIR / 256), dim3(256), 0, stream>>>(ws);
    pair_error_t<<<dim3(4 * 32 * NC), dim3(256), 0, stream>>>(pred, gt, ws);
    argmin_out<<<dim3(1), dim3(64), 0, stream>>>(ws, out);
}

// Round 3
// 339.548 us; speedup vs baseline: 1.3613x; 1.3613x over previous
//
#include <hip/hip_runtime.h>
#include <math.h>

#define P_ 32
#define G_ 256
#define NV 6890
#define M_ (2 * NV)          // 13780 joint points per sample
#define MP 13824             // padded vertex stride for SoA (multiple of 256)
#define NPAIR (P_ * G_)      // 8192

// ---------------- workspace layout ----------------
struct WS {
    float mu_p[P_][3];
    float var_p[P_];
    float mu_g[G_][3];
    float At[NPAIR][12];          // A = scale*R (9) then t (3); pair = g*32 + p
    float Kmat[NPAIR][9];         // full cross-covariance (pre mean-subtraction)
    float pair_err[NPAIR];        // mean v2v error per pair
    float predT[P_][3][MP];       // SoA transposed pred  (5.3 MB)
    float gtT[G_][3][MP];         // SoA transposed gt   (42.5 MB)
};

// ---------------- block reduction (valid on thread 0) ----------------
__device__ inline double block_reduce(double v, double* smem) {
#pragma unroll
    for (int off = 32; off > 0; off >>= 1) v += __shfl_down(v, off, 64);
    int wid  = threadIdx.x >> 6;
    int lane = threadIdx.x & 63;
    __syncthreads();
    if (lane == 0) smem[wid] = v;
    __syncthreads();
    double r = 0.0;
    if (threadIdx.x == 0) {
        int nw = blockDim.x >> 6;
        for (int w = 0; w < nw; ++w) r += smem[w];
    }
    return r;
}

// ---------------- kernel 1: pred stats (mu_p, var_p) ----------------
__global__ __launch_bounds__(256) void pred_stats(const float* __restrict__ pred, WS* ws) {
    int p = blockIdx.x;
    const float* base = pred + (size_t)p * M_ * 3;
    double sx = 0, sy = 0, sz = 0, sq = 0;
    for (int i = threadIdx.x; i < M_; i += 256) {
        float x = base[3 * i + 0];
        float y = base[3 * i + 1];
        float z = base[3 * i + 2];
        sx += x; sy += y; sz += z;
        sq += (double)x * x + (double)y * y + (double)z * z;
    }
    __shared__ double smem[4];
    double rx = block_reduce(sx, smem);
    double ry = block_reduce(sy, smem);
    double rz = block_reduce(sz, smem);
    double rq = block_reduce(sq, smem);
    if (threadIdx.x == 0) {
        double mx = rx / M_, my = ry / M_, mz = rz / M_;
        ws->mu_p[p][0] = (float)mx;
        ws->mu_p[p][1] = (float)my;
        ws->mu_p[p][2] = (float)mz;
        ws->var_p[p] = (float)(rq - (mx * mx + my * my + mz * mz) * (double)M_);
    }
}

// ---------------- kernel 2: gt stats (mu_g) ----------------
__global__ __launch_bounds__(256) void gt_stats(const float* __restrict__ gt, WS* ws) {
    int g = blockIdx.x;
    const float* base = gt + (size_t)g * M_ * 3;
    double sx = 0, sy = 0, sz = 0;
    for (int i = threadIdx.x; i < M_; i += 256) {
        sx += base[3 * i + 0];
        sy += base[3 * i + 1];
        sz += base[3 * i + 2];
    }
    __shared__ double smem[4];
    double rx = block_reduce(sx, smem);
    double ry = block_reduce(sy, smem);
    double rz = block_reduce(sz, smem);
    if (threadIdx.x == 0) {
        ws->mu_g[g][0] = (float)(rx / M_);
        ws->mu_g[g][1] = (float)(ry / M_);
        ws->mu_g[g][2] = (float)(rz / M_);
    }
}

// ---------------- kernel 0: AoS -> SoA transpose ----------------
// 14 chunk-blocks of 256 threads per sample; thread handles 4 vertices.
__global__ __launch_bounds__(256) void transpose_soa(const float* __restrict__ src,
                                                     float* __restrict__ dst) {
    int s = blockIdx.x / 14;
    int chunk = blockIdx.x % 14;
    int v0 = 4 * (chunk * 256 + threadIdx.x);
    if (v0 >= M_) return;
    const float4* p = (const float4*)(src + (size_t)s * (M_ * 3) + (size_t)v0 * 3);
    float4 a = p[0], b = p[1], c = p[2];
    float* d = dst + (size_t)s * 3 * MP;
    *(float4*)(d + v0)          = make_float4(a.x, a.w, b.z, c.y);  // x0..x3
    *(float4*)(d + MP + v0)     = make_float4(a.y, b.x, b.w, c.z);  // y0..y3
    *(float4*)(d + 2 * MP + v0) = make_float4(a.z, b.y, c.x, c.w);  // z0..z3
}

// ---------------- kernel 3: register-tiled cross-covariance ----------------
// grid: 512 blocks of 256; block = (ptile of 4) x (gtile of 4); thread owns all
// 16 pairs, strides v by 256. No LDS in main loop.
template <bool SOA>
__global__ __launch_bounds__(256, 2) void crosscov_t2(const float* __restrict__ pA,
                                                      const float* __restrict__ gA,
                                                      WS* __restrict__ ws) {
    int bx = blockIdx.x;
    int pbase = (bx & 7) * 4;
    int gbase = (bx >> 3) * 4;
    int t = threadIdx.x;

    float acc[16][9];
#pragma unroll
    for (int q = 0; q < 16; ++q)
#pragma unroll
        for (int j = 0; j < 9; ++j) acc[q][j] = 0.f;

    for (int v = t; v < M_; v += 256) {
        float px[4], py[4], pz[4];
#pragma unroll
        for (int j = 0; j < 4; ++j) {
            if (SOA) {
                const float* b = pA + (size_t)(pbase + j) * 3 * MP + v;
                px[j] = b[0]; py[j] = b[MP]; pz[j] = b[2 * MP];
            } else {
                const float* b = pA + (size_t)(pbase + j) * (M_ * 3) + 3 * (size_t)v;
                px[j] = b[0]; py[j] = b[1]; pz[j] = b[2];
            }
        }
#pragma unroll
        for (int gg = 0; gg < 4; ++gg) {
            float gx, gy, gz;
            if (SOA) {
                const float* b = gA + (size_t)(gbase + gg) * 3 * MP + v;
                gx = b[0]; gy = b[MP]; gz = b[2 * MP];
            } else {
                const float* b = gA + (size_t)(gbase + gg) * (M_ * 3) + 3 * (size_t)v;
                gx = b[0]; gy = b[1]; gz = b[2];
            }
#pragma unroll
            for (int pp = 0; pp < 4; ++pp) {
                float* a = acc[gg * 4 + pp];
                a[0] = fmaf(px[pp], gx, a[0]);
                a[1] = fmaf(px[pp], gy, a[1]);
                a[2] = fmaf(px[pp], gz, a[2]);
                a[3] = fmaf(py[pp], gx, a[3]);
                a[4] = fmaf(py[pp], gy, a[4]);
                a[5] = fmaf(py[pp], gz, a[5]);
                a[6] = fmaf(pz[pp], gx, a[6]);
                a[7] = fmaf(pz[pp], gy, a[7]);
                a[8] = fmaf(pz[pp], gz, a[8]);
            }
        }
    }

    // 2-step xor reduce (quads of lanes hold identical sums afterwards)
#pragma unroll
    for (int q = 0; q < 16; ++q)
#pragma unroll
        for (int j = 0; j < 9; ++j) {
            float v = acc[q][j];
            v += __shfl_xor(v, 1);
            v += __shfl_xor(v, 2);
            acc[q][j] = v;
        }

    __shared__ float part[144 * 65];   // 144 values x 64 quad-partials (+pad)
    int lane = t & 63, wave = t >> 6;
    int sub = lane & 3;
    int col = wave * 16 + (lane >> 2);
#pragma unroll
    for (int q = 0; q < 16; ++q)
#pragma unroll
        for (int j = 0; j < 9; ++j) {
            int f = q * 9 + j;
            if ((f & 3) == sub) part[f * 65 + col] = acc[q][j];
        }
    __syncthreads();
    if (t < 144) {
        float s = 0.f;
        const float* row = &part[t * 65];
        for (int c = 0; c < 64; ++c) s += row[c];
        int gg = t / 36, pp = (t / 9) & 3, j = t % 9;
        ws->Kmat[(gbase + gg) * P_ + (pbase + pp)][j] = s;
    }
}

// ---------------- kernel 4: per-pair SVD -> A = scale*R, t ----------------
__global__ __launch_bounds__(256) void pair_svd(WS* ws) {
    int pair = blockIdx.x * blockDim.x + threadIdx.x;
    if (pair >= NPAIR) return;
    int p = pair & 31;
    int g = pair >> 5;

    double K[3][3];
#pragma unroll
    for (int a = 0; a < 3; ++a)
#pragma unroll
        for (int b = 0; b < 3; ++b) K[a][b] = (double)ws->Kmat[pair][3 * a + b];
    {   // subtract M * mu_p mu_g^T
        double mp[3] = { ws->mu_p[p][0], ws->mu_p[p][1], ws->mu_p[p][2] };
        double mg[3] = { ws->mu_g[g][0], ws->mu_g[g][1], ws->mu_g[g][2] };
#pragma unroll
        for (int a = 0; a < 3; ++a)
#pragma unroll
            for (int b = 0; b < 3; ++b)
                K[a][b] -= (double)M_ * mp[a] * mg[b];
    }

    // S = K^T K (symmetric PSD)
    double S[3][3];
#pragma unroll
    for (int a = 0; a < 3; ++a)
#pragma unroll
        for (int b = 0; b < 3; ++b) {
            double acc = 0.0;
#pragma unroll
            for (int c = 0; c < 3; ++c) acc += K[c][a] * K[c][b];
            S[a][b] = acc;
        }

    // Jacobi eigendecomposition S = V Lambda V^T
    double V[3][3] = { {1, 0, 0}, {0, 1, 0}, {0, 0, 1} };
    double tr = S[0][0] + S[1][1] + S[2][2];
    double tol = 1e-30 * tr * tr + 1e-300;
    const int PP[3] = {0, 0, 1};
    const int QQ[3] = {1, 2, 2};
    for (int sweep = 0; sweep < 30; ++sweep) {
        double off = S[0][1] * S[0][1] + S[0][2] * S[0][2] + S[1][2] * S[1][2];
        if (off <= tol) break;
        for (int r3 = 0; r3 < 3; ++r3) {
            int pq = PP[r3], qq = QQ[r3];
            double apq = S[pq][qq];
            if (apq == 0.0) continue;
            double theta = (S[qq][qq] - S[pq][pq]) / (2.0 * apq);
            double tt = copysign(1.0, theta) / (fabs(theta) + sqrt(theta * theta + 1.0));
            double c = 1.0 / sqrt(tt * tt + 1.0);
            double sj = tt * c;
            for (int r = 0; r < 3; ++r) {
                double srp = S[r][pq], srq = S[r][qq];
                S[r][pq] = c * srp - sj * srq;
                S[r][qq] = sj * srp + c * srq;
            }
            for (int cc = 0; cc < 3; ++cc) {
                double spr = S[pq][cc], sqr = S[qq][cc];
                S[pq][cc] = c * spr - sj * sqr;
                S[qq][cc] = sj * spr + c * sqr;
            }
            for (int r = 0; r < 3; ++r) {
                double vrp = V[r][pq], vrq = V[r][qq];
                V[r][pq] = c * vrp - sj * vrq;
                V[r][qq] = sj * vrp + c * vrq;
            }
        }
    }

    // sort eigenpairs descending
    double lam[3] = { S[0][0], S[1][1], S[2][2] };
    int idx[3] = { 0, 1, 2 };
    if (lam[idx[0]] < lam[idx[1]]) { int tt = idx[0]; idx[0] = idx[1]; idx[1] = tt; }
    if (lam[idx[0]] < lam[idx[2]]) { int tt = idx[0]; idx[0] = idx[2]; idx[2] = tt; }
    if (lam[idx[1]] < lam[idx[2]]) { int tt = idx[1]; idx[1] = idx[2]; idx[2] = tt; }
    double Vs[3][3];
    double sv[3];
#pragma unroll
    for (int i = 0; i < 3; ++i) {
        double l = lam[idx[i]];
        sv[i] = sqrt(l > 0.0 ? l : 0.0);
        for (int r = 0; r < 3; ++r) Vs[r][i] = V[r][idx[i]];
    }

    // U columns: u_i = K v_i / s_i
    double U[3][3];
#pragma unroll
    for (int i = 0; i < 3; ++i) {
        double kx = K[0][0] * Vs[0][i] + K[0][1] * Vs[1][i] + K[0][2] * Vs[2][i];
        double ky = K[1][0] * Vs[0][i] + K[1][1] * Vs[1][i] + K[1][2] * Vs[2][i];
        double kz = K[2][0] * Vs[0][i] + K[2][1] * Vs[1][i] + K[2][2] * Vs[2][i];
        double inv = (sv[i] > 1e-12 * sv[0] && sv[i] > 0.0) ? 1.0 / sv[i] : 0.0;
        U[0][i] = kx * inv; U[1][i] = ky * inv; U[2][i] = kz * inv;
    }
    if (sv[2] <= 1e-12 * sv[0] || sv[0] == 0.0) {
        U[0][2] = U[1][0] * U[2][1] - U[2][0] * U[1][1];
        U[1][2] = U[2][0] * U[0][1] - U[0][0] * U[2][1];
        U[2][2] = U[0][0] * U[1][1] - U[1][0] * U[0][1];
    }

    double detK = K[0][0] * (K[1][1] * K[2][2] - K[1][2] * K[2][1])
                - K[0][1] * (K[1][0] * K[2][2] - K[1][2] * K[2][0])
                + K[0][2] * (K[1][0] * K[2][1] - K[1][1] * K[2][0]);
    double d = (detK >= 0.0) ? 1.0 : -1.0;

    double varp = (double)ws->var_p[p];
    double scale = (sv[0] + sv[1] + d * sv[2]) / varp;

    float A[9];
#pragma unroll
    for (int a = 0; a < 3; ++a)
#pragma unroll
        for (int b = 0; b < 3; ++b) {
            double r = Vs[a][0] * U[b][0] + Vs[a][1] * U[b][1] + d * Vs[a][2] * U[b][2];
            A[3 * a + b] = (float)(scale * r);
        }
    double mp[3] = { ws->mu_p[p][0], ws->mu_p[p][1], ws->mu_p[p][2] };
    double mg[3] = { ws->mu_g[g][0], ws->mu_g[g][1], ws->mu_g[g][2] };
    float tvec[3];
#pragma unroll
    for (int a = 0; a < 3; ++a)
        tvec[a] = (float)(mg[a] - ((double)A[3 * a + 0] * mp[0] + (double)A[3 * a + 1] * mp[1] +
                                   (double)A[3 * a + 2] * mp[2]));

#pragma unroll
    for (int j = 0; j < 9; ++j) ws->At[pair][j] = A[j];
#pragma unroll
    for (int j = 0; j < 3; ++j) ws->At[pair][9 + j] = tvec[j];
}

// ---------------- kernel 5: register-tiled v2v error ----------------
// grid: 1024 blocks of 256; block = (ptile of 2) x (gtile of 4); thread owns
// all 8 pairs (At in regs), strides v by 256. No LDS in main loop.
template <bool SOA>
__global__ __launch_bounds__(256, 3) void pair_error_t2(const float* __restrict__ pA,
                                                        const float* __restrict__ gA,
                                                        WS* __restrict__ ws) {
    int bx = blockIdx.x;
    int pbase = (bx & 15) * 2;
    int gbase = (bx >> 4) * 4;
    int t = threadIdx.x;

    float A[8][12];
#pragma unroll
    for (int gg = 0; gg < 4; ++gg)
#pragma unroll
        for (int pp = 0; pp < 2; ++pp) {
            int pair = (gbase + gg) * P_ + (pbase + pp);
#pragma unroll
            for (int j = 0; j < 12; ++j) A[gg * 2 + pp][j] = ws->At[pair][j];
        }

    float acc[8];
#pragma unroll
    for (int q = 0; q < 8; ++q) acc[q] = 0.f;

    for (int v = t; v < M_; v += 256) {
        float px[2], py[2], pz[2];
#pragma unroll
        for (int j = 0; j < 2; ++j) {
            if (SOA) {
                const float* b = pA + (size_t)(pbase + j) * 3 * MP + v;
                px[j] = b[0]; py[j] = b[MP]; pz[j] = b[2 * MP];
            } else {
                const float* b = pA + (size_t)(pbase + j) * (M_ * 3) + 3 * (size_t)v;
                px[j] = b[0]; py[j] = b[1]; pz[j] = b[2];
            }
        }
#pragma unroll
        for (int gg = 0; gg < 4; ++gg) {
            float gx, gy, gz;
            if (SOA) {
                const float* b = gA + (size_t)(gbase + gg) * 3 * MP + v;
                gx = b[0]; gy = b[MP]; gz = b[2 * MP];
            } else {
                const float* b = gA + (size_t)(gbase + gg) * (M_ * 3) + 3 * (size_t)v;
                gx = b[0]; gy = b[1]; gz = b[2];
            }
#pragma unroll
            for (int pp = 0; pp < 2; ++pp) {
                const float* a = A[gg * 2 + pp];
                float dx = fmaf(a[0], px[pp], fmaf(a[1], py[pp], fmaf(a[2], pz[pp], a[9])))  - gx;
                float dy = fmaf(a[3], px[pp], fmaf(a[4], py[pp], fmaf(a[5], pz[pp], a[10]))) - gy;
                float dz = fmaf(a[6], px[pp], fmaf(a[7], py[pp], fmaf(a[8], pz[pp], a[11]))) - gz;
                float n2 = fmaf(dx, dx, fmaf(dy, dy, dz * dz));
                acc[gg * 2 + pp] += __builtin_amdgcn_sqrtf(n2);
            }
        }
    }

#pragma unroll
    for (int q = 0; q < 8; ++q) {
        float v = acc[q];
        v += __shfl_xor(v, 1);
        v += __shfl_xor(v, 2);
        v += __shfl_xor(v, 4);
        v += __shfl_xor(v, 8);
        v += __shfl_xor(v, 16);
        v += __shfl_xor(v, 32);
        acc[q] = v;
    }
    __shared__ float part[8][4];
    int lane = t & 63, wave = t >> 6;
    if (lane < 8) part[lane][wave] = acc[lane];
    __syncthreads();
    if (t < 8) {
        float s = part[t][0] + part[t][1] + part[t][2] + part[t][3];
        int gg = t >> 1, pp = t & 1;
        ws->pair_err[(gbase + gg) * P_ + (pbase + pp)] = s / (float)M_;
    }
}

// ---------------- kernel 6: argmin over gallery + write outputs ----------------
__global__ void argmin_out(const WS* __restrict__ ws, float* __restrict__ out) {
    int p = threadIdx.x;
    if (p >= P_) return;
    float best = 3.4e38f;
    int bi = 0;
    for (int g = 0; g < G_; ++g) {
        float e = ws->pair_err[g * P_ + p];
        if (e < best) { best = e; bi = g; }
    }
    out[p] = (float)bi;
    out[P_ + p] = best;
}

extern "C" void kernel_launch(void* const* d_in, const int* in_sizes, int n_in,
                              void* d_out, int out_size, void* d_ws, size_t ws_size,
                              hipStream_t stream) {
    const float* pred = (const float*)d_in[0];   // (32, 2, 6890, 3)
    const float* gt   = (const float*)d_in[1];   // (256, 2, 6890, 3)
    float* out = (float*)d_out;                  // 64 floats: mapping(32) | min_error(32)
    WS* ws = (WS*)d_ws;
    bool soa = ws_size >= sizeof(WS);            // ~48.5 MB needed for SoA path

    pred_stats<<<dim3(P_), dim3(256), 0, stream>>>(pred, ws);
    gt_stats<<<dim3(G_), dim3(256), 0, stream>>>(gt, ws);

    if (soa) {
        transpose_soa<<<dim3(P_ * 14), dim3(256), 0, stream>>>(pred, &ws->predT[0][0][0]);
        transpose_soa<<<dim3(G_ * 14), dim3(256), 0, stream>>>(gt, &ws->gtT[0][0][0]);
        crosscov_t2<true><<<dim3(512), dim3(256), 0, stream>>>(&ws->predT[0][0][0],
                                                               &ws->gtT[0][0][0], ws);
        pair_svd<<<dim3(NPAIR / 256), dim3(256), 0, stream>>>(ws);
        pair_error_t2<true><<<dim3(1024), dim3(256), 0, stream>>>(&ws->predT[0][0][0],
                                                                  &ws->gtT[0][0][0], ws);
    } else {
        crosscov_t2<false><<<dim3(512), dim3(256), 0, stream>>>(pred, gt, ws);
        pair_svd<<<dim3(NPAIR / 256), dim3(256), 0, stream>>>(ws);
        pair_error_t2<false><<<dim3(1024), dim3(256), 0, stream>>>(pred, gt, ws);
    }
    argmin_out<<<dim3(1), dim3(64), 0, stream>>>(ws, out);
}

// Round 4
// 283.763 us; speedup vs baseline: 1.6289x; 1.1966x over previous
//
#include <hip/hip_runtime.h>
#include <math.h>

#define P_ 32
#define G_ 256
#define NV 6890
#define M_ (2 * NV)          // 13780 joint points per sample
#define QUADS (M_ / 4)       // 3445 vertex-quads (exact)
#define NPAIR (P_ * G_)      // 8192
#define KC 2                 // v-chunks for the pair kernels

// ---------------- workspace layout ----------------
struct WS {
    float mu_p[P_][3];
    float var_p[P_];
    float mu_g[G_][3];
    float At[NPAIR][12];          // A = scale*R (9) then t (3); pair = g*32 + p
    float partK[KC][NPAIR][9];    // per-chunk partial cross-covariance
    float partE[KC][NPAIR];       // per-chunk partial sum of v2v norms
};

// ---------------- block reduction (valid on thread 0) ----------------
__device__ inline double block_reduce(double v, double* smem) {
#pragma unroll
    for (int off = 32; off > 0; off >>= 1) v += __shfl_down(v, off, 64);
    int wid  = threadIdx.x >> 6;
    int lane = threadIdx.x & 63;
    __syncthreads();
    if (lane == 0) smem[wid] = v;
    __syncthreads();
    double r = 0.0;
    if (threadIdx.x == 0) {
        int nw = blockDim.x >> 6;
        for (int w = 0; w < nw; ++w) r += smem[w];
    }
    return r;
}

// ---------------- kernel 1: stats for pred (mu,var) and gt (mu) ----------------
// blocks 0..31 = pred samples, 32..287 = gt samples. AoS float4-quad loads.
__global__ __launch_bounds__(256) void stats_all(const float* __restrict__ pred,
                                                 const float* __restrict__ gt, WS* ws) {
    int b = blockIdx.x;
    bool isP = (b < P_);
    const float* base = isP ? pred + (size_t)b * (M_ * 3)
                            : gt + (size_t)(b - P_) * (M_ * 3);
    double sx = 0, sy = 0, sz = 0, sq = 0;
    for (int q = threadIdx.x; q < QUADS; q += 256) {
        const float4* p4 = (const float4*)(base + 12 * (size_t)q);
        float4 a = p4[0], c = p4[1], d = p4[2];
        // verts: (a.x,a.y,a.z) (a.w,c.x,c.y) (c.z,c.w,d.x) (d.y,d.z,d.w)
        sx += (double)a.x + (double)a.w + (double)c.z + (double)d.y;
        sy += (double)a.y + (double)c.x + (double)c.w + (double)d.z;
        sz += (double)a.z + (double)c.y + (double)d.x + (double)d.w;
        if (isP) {
            sq += (double)a.x * a.x + (double)a.y * a.y + (double)a.z * a.z +
                  (double)a.w * a.w + (double)c.x * c.x + (double)c.y * c.y +
                  (double)c.z * c.z + (double)c.w * c.w + (double)d.x * d.x +
                  (double)d.y * d.y + (double)d.z * d.z + (double)d.w * d.w;
        }
    }
    __shared__ double smem[4];
    double rx = block_reduce(sx, smem);
    double ry = block_reduce(sy, smem);
    double rz = block_reduce(sz, smem);
    double rq = block_reduce(sq, smem);
    if (threadIdx.x == 0) {
        double mx = rx / M_, my = ry / M_, mz = rz / M_;
        if (isP) {
            ws->mu_p[b][0] = (float)mx;
            ws->mu_p[b][1] = (float)my;
            ws->mu_p[b][2] = (float)mz;
            ws->var_p[b] = (float)(rq - (mx * mx + my * my + mz * mz) * (double)M_);
        } else {
            ws->mu_g[b - P_][0] = (float)mx;
            ws->mu_g[b - P_][1] = (float)my;
            ws->mu_g[b - P_][2] = (float)mz;
        }
    }
}

// load one 4-vertex quad (x[4],y[4],z[4]) from AoS via 3 float4 loads
#define LOAD_QUAD(BASE, Q, X, Y, Z)                                     \
    {                                                                   \
        const float4* _p4 = (const float4*)((BASE) + 12 * (size_t)(Q)); \
        float4 _a = _p4[0], _c = _p4[1], _d = _p4[2];                   \
        X[0] = _a.x; X[1] = _a.w; X[2] = _c.z; X[3] = _d.y;             \
        Y[0] = _a.y; Y[1] = _c.x; Y[2] = _c.w; Y[3] = _d.z;             \
        Z[0] = _a.z; Z[1] = _c.y; Z[2] = _d.x; Z[3] = _d.w;             \
    }

// ---------------- kernel 2: register-tiled cross-covariance (2p x 2g) ----------------
// grid: 16 ptiles x 128 gtiles x KC chunks; thread owns 4 pairs, 4 verts/iter
__global__ __launch_bounds__(256, 4) void crosscov_q(const float* __restrict__ pred,
                                                     const float* __restrict__ gt,
                                                     WS* __restrict__ ws) {
    int bx = blockIdx.x;
    int pbase = (bx & 15) * 2;
    int gbase = ((bx >> 4) & 127) * 2;
    int kc = bx >> 11;
    int qbeg = (QUADS * kc) / KC, qend = (QUADS * (kc + 1)) / KC;
    int t = threadIdx.x;

    const float* pb0 = pred + (size_t)pbase * (M_ * 3);
    const float* pb1 = pred + (size_t)(pbase + 1) * (M_ * 3);
    const float* gb0 = gt + (size_t)gbase * (M_ * 3);
    const float* gb1 = gt + (size_t)(gbase + 1) * (M_ * 3);

    float acc[4][9];
#pragma unroll
    for (int q = 0; q < 4; ++q)
#pragma unroll
        for (int j = 0; j < 9; ++j) acc[q][j] = 0.f;

    for (int q = qbeg + t; q < qend; q += 256) {
        float px[2][4], py[2][4], pz[2][4];
        float gx[2][4], gy[2][4], gz[2][4];
        LOAD_QUAD(pb0, q, px[0], py[0], pz[0]);
        LOAD_QUAD(pb1, q, px[1], py[1], pz[1]);
        LOAD_QUAD(gb0, q, gx[0], gy[0], gz[0]);
        LOAD_QUAD(gb1, q, gx[1], gy[1], gz[1]);
#pragma unroll
        for (int gg = 0; gg < 2; ++gg)
#pragma unroll
            for (int pp = 0; pp < 2; ++pp) {
                float* a = acc[gg * 2 + pp];
#pragma unroll
                for (int k = 0; k < 4; ++k) {
                    a[0] = fmaf(px[pp][k], gx[gg][k], a[0]);
                    a[1] = fmaf(px[pp][k], gy[gg][k], a[1]);
                    a[2] = fmaf(px[pp][k], gz[gg][k], a[2]);
                    a[3] = fmaf(py[pp][k], gx[gg][k], a[3]);
                    a[4] = fmaf(py[pp][k], gy[gg][k], a[4]);
                    a[5] = fmaf(py[pp][k], gz[gg][k], a[5]);
                    a[6] = fmaf(pz[pp][k], gx[gg][k], a[6]);
                    a[7] = fmaf(pz[pp][k], gy[gg][k], a[7]);
                    a[8] = fmaf(pz[pp][k], gz[gg][k], a[8]);
                }
            }
    }

    // full-wave butterfly reduce -> every lane holds wave total
#pragma unroll
    for (int q = 0; q < 4; ++q)
#pragma unroll
        for (int j = 0; j < 9; ++j) {
            float v = acc[q][j];
            v += __shfl_xor(v, 1);  v += __shfl_xor(v, 2);
            v += __shfl_xor(v, 4);  v += __shfl_xor(v, 8);
            v += __shfl_xor(v, 16); v += __shfl_xor(v, 32);
            acc[q][j] = v;
        }
    __shared__ float part[4][36];
    int lane = t & 63, wave = t >> 6;
    if (lane == 0) {
#pragma unroll
        for (int q = 0; q < 4; ++q)
#pragma unroll
            for (int j = 0; j < 9; ++j) part[wave][q * 9 + j] = acc[q][j];
    }
    __syncthreads();
    if (t < 36) {
        float s = part[0][t] + part[1][t] + part[2][t] + part[3][t];
        int idx = t / 9, j = t % 9;
        int gg = idx >> 1, pp = idx & 1;
        ws->partK[kc][(gbase + gg) * P_ + (pbase + pp)][j] = s;
    }
}

// ---------------- kernel 3: per-pair SVD -> A = scale*R, t ----------------
__global__ __launch_bounds__(256) void pair_svd(WS* ws) {
    int pair = blockIdx.x * blockDim.x + threadIdx.x;
    if (pair >= NPAIR) return;
    int p = pair & 31;
    int g = pair >> 5;

    double K[3][3];
#pragma unroll
    for (int a = 0; a < 3; ++a)
#pragma unroll
        for (int b = 0; b < 3; ++b) {
            double s = 0.0;
#pragma unroll
            for (int kc = 0; kc < KC; ++kc) s += (double)ws->partK[kc][pair][3 * a + b];
            K[a][b] = s;
        }
    {   // subtract M * mu_p mu_g^T
        double mp[3] = { ws->mu_p[p][0], ws->mu_p[p][1], ws->mu_p[p][2] };
        double mg[3] = { ws->mu_g[g][0], ws->mu_g[g][1], ws->mu_g[g][2] };
#pragma unroll
        for (int a = 0; a < 3; ++a)
#pragma unroll
            for (int b = 0; b < 3; ++b)
                K[a][b] -= (double)M_ * mp[a] * mg[b];
    }

    // S = K^T K (symmetric PSD)
    double S[3][3];
#pragma unroll
    for (int a = 0; a < 3; ++a)
#pragma unroll
        for (int b = 0; b < 3; ++b) {
            double acc = 0.0;
#pragma unroll
            for (int c = 0; c < 3; ++c) acc += K[c][a] * K[c][b];
            S[a][b] = acc;
        }

    // Jacobi eigendecomposition S = V Lambda V^T
    double V[3][3] = { {1, 0, 0}, {0, 1, 0}, {0, 0, 1} };
    double tr = S[0][0] + S[1][1] + S[2][2];
    double tol = 1e-30 * tr * tr + 1e-300;
    const int PP[3] = {0, 0, 1};
    const int QQ[3] = {1, 2, 2};
    for (int sweep = 0; sweep < 30; ++sweep) {
        double off = S[0][1] * S[0][1] + S[0][2] * S[0][2] + S[1][2] * S[1][2];
        if (off <= tol) break;
        for (int r3 = 0; r3 < 3; ++r3) {
            int pq = PP[r3], qq = QQ[r3];
            double apq = S[pq][qq];
            if (apq == 0.0) continue;
            double theta = (S[qq][qq] - S[pq][pq]) / (2.0 * apq);
            double tt = copysign(1.0, theta) / (fabs(theta) + sqrt(theta * theta + 1.0));
            double c = 1.0 / sqrt(tt * tt + 1.0);
            double sj = tt * c;
            for (int r = 0; r < 3; ++r) {
                double srp = S[r][pq], srq = S[r][qq];
                S[r][pq] = c * srp - sj * srq;
                S[r][qq] = sj * srp + c * srq;
            }
            for (int cc = 0; cc < 3; ++cc) {
                double spr = S[pq][cc], sqr = S[qq][cc];
                S[pq][cc] = c * spr - sj * sqr;
                S[qq][cc] = sj * spr + c * sqr;
            }
            for (int r = 0; r < 3; ++r) {
                double vrp = V[r][pq], vrq = V[r][qq];
                V[r][pq] = c * vrp - sj * vrq;
                V[r][qq] = sj * vrp + c * vrq;
            }
        }
    }

    // sort eigenpairs descending
    double lam[3] = { S[0][0], S[1][1], S[2][2] };
    int idx[3] = { 0, 1, 2 };
    if (lam[idx[0]] < lam[idx[1]]) { int tt = idx[0]; idx[0] = idx[1]; idx[1] = tt; }
    if (lam[idx[0]] < lam[idx[2]]) { int tt = idx[0]; idx[0] = idx[2]; idx[2] = tt; }
    if (lam[idx[1]] < lam[idx[2]]) { int tt = idx[1]; idx[1] = idx[2]; idx[2] = tt; }
    double Vs[3][3];
    double sv[3];
#pragma unroll
    for (int i = 0; i < 3; ++i) {
        double l = lam[idx[i]];
        sv[i] = sqrt(l > 0.0 ? l : 0.0);
        for (int r = 0; r < 3; ++r) Vs[r][i] = V[r][idx[i]];
    }

    // U columns: u_i = K v_i / s_i
    double U[3][3];
#pragma unroll
    for (int i = 0; i < 3; ++i) {
        double kx = K[0][0] * Vs[0][i] + K[0][1] * Vs[1][i] + K[0][2] * Vs[2][i];
        double ky = K[1][0] * Vs[0][i] + K[1][1] * Vs[1][i] + K[1][2] * Vs[2][i];
        double kz = K[2][0] * Vs[0][i] + K[2][1] * Vs[1][i] + K[2][2] * Vs[2][i];
        double inv = (sv[i] > 1e-12 * sv[0] && sv[i] > 0.0) ? 1.0 / sv[i] : 0.0;
        U[0][i] = kx * inv; U[1][i] = ky * inv; U[2][i] = kz * inv;
    }
    if (sv[2] <= 1e-12 * sv[0] || sv[0] == 0.0) {
        U[0][2] = U[1][0] * U[2][1] - U[2][0] * U[1][1];
        U[1][2] = U[2][0] * U[0][1] - U[0][0] * U[2][1];
        U[2][2] = U[0][0] * U[1][1] - U[1][0] * U[0][1];
    }

    double detK = K[0][0] * (K[1][1] * K[2][2] - K[1][2] * K[2][1])
                - K[0][1] * (K[1][0] * K[2][2] - K[1][2] * K[2][0])
                + K[0][2] * (K[1][0] * K[2][1] - K[1][1] * K[2][0]);
    double d = (detK >= 0.0) ? 1.0 : -1.0;

    double varp = (double)ws->var_p[p];
    double scale = (sv[0] + sv[1] + d * sv[2]) / varp;

    float A[9];
#pragma unroll
    for (int a = 0; a < 3; ++a)
#pragma unroll
        for (int b = 0; b < 3; ++b) {
            double r = Vs[a][0] * U[b][0] + Vs[a][1] * U[b][1] + d * Vs[a][2] * U[b][2];
            A[3 * a + b] = (float)(scale * r);
        }
    double mp[3] = { ws->mu_p[p][0], ws->mu_p[p][1], ws->mu_p[p][2] };
    double mg[3] = { ws->mu_g[g][0], ws->mu_g[g][1], ws->mu_g[g][2] };
    float tvec[3];
#pragma unroll
    for (int a = 0; a < 3; ++a)
        tvec[a] = (float)(mg[a] - ((double)A[3 * a + 0] * mp[0] + (double)A[3 * a + 1] * mp[1] +
                                   (double)A[3 * a + 2] * mp[2]));

#pragma unroll
    for (int j = 0; j < 9; ++j) ws->At[pair][j] = A[j];
#pragma unroll
    for (int j = 0; j < 3; ++j) ws->At[pair][9 + j] = tvec[j];
}

// ---------------- kernel 4: register-tiled v2v error (2p x 4g) ----------------
// grid: 16 ptiles x 64 gtiles x KC chunks; thread owns 8 pairs, 4 verts/iter
__global__ __launch_bounds__(256, 3) void pair_error_q(const float* __restrict__ pred,
                                                       const float* __restrict__ gt,
                                                       WS* __restrict__ ws) {
    int bx = blockIdx.x;
    int pbase = (bx & 15) * 2;
    int gbase = ((bx >> 4) & 63) * 4;
    int kc = bx >> 10;
    int qbeg = (QUADS * kc) / KC, qend = (QUADS * (kc + 1)) / KC;
    int t = threadIdx.x;

    float A[8][12];
#pragma unroll
    for (int gg = 0; gg < 4; ++gg)
#pragma unroll
        for (int pp = 0; pp < 2; ++pp) {
            int pair = (gbase + gg) * P_ + (pbase + pp);
#pragma unroll
            for (int j = 0; j < 12; ++j) A[gg * 2 + pp][j] = ws->At[pair][j];
        }

    const float* pb0 = pred + (size_t)pbase * (M_ * 3);
    const float* pb1 = pred + (size_t)(pbase + 1) * (M_ * 3);

    float acc[8];
#pragma unroll
    for (int q = 0; q < 8; ++q) acc[q] = 0.f;

    for (int q = qbeg + t; q < qend; q += 256) {
        float px[2][4], py[2][4], pz[2][4];
        LOAD_QUAD(pb0, q, px[0], py[0], pz[0]);
        LOAD_QUAD(pb1, q, px[1], py[1], pz[1]);
#pragma unroll
        for (int gg = 0; gg < 4; ++gg) {
            float gx[4], gy[4], gz[4];
            const float* gb = gt + (size_t)(gbase + gg) * (M_ * 3);
            LOAD_QUAD(gb, q, gx, gy, gz);
#pragma unroll
            for (int pp = 0; pp < 2; ++pp) {
                const float* a = A[gg * 2 + pp];
                float s = 0.f;
#pragma unroll
                for (int k = 0; k < 4; ++k) {
                    float dx = fmaf(a[0], px[pp][k], fmaf(a[1], py[pp][k], fmaf(a[2], pz[pp][k], a[9])))  - gx[k];
                    float dy = fmaf(a[3], px[pp][k], fmaf(a[4], py[pp][k], fmaf(a[5], pz[pp][k], a[10]))) - gy[k];
                    float dz = fmaf(a[6], px[pp][k], fmaf(a[7], py[pp][k], fmaf(a[8], pz[pp][k], a[11]))) - gz[k];
                    s += __builtin_amdgcn_sqrtf(fmaf(dx, dx, fmaf(dy, dy, dz * dz)));
                }
                acc[gg * 2 + pp] += s;
            }
        }
    }

#pragma unroll
    for (int q = 0; q < 8; ++q) {
        float v = acc[q];
        v += __shfl_xor(v, 1);  v += __shfl_xor(v, 2);
        v += __shfl_xor(v, 4);  v += __shfl_xor(v, 8);
        v += __shfl_xor(v, 16); v += __shfl_xor(v, 32);
        acc[q] = v;
    }
    __shared__ float part[4][8];
    int lane = t & 63, wave = t >> 6;
    if (lane == 0) {
#pragma unroll
        for (int q = 0; q < 8; ++q) part[wave][q] = acc[q];
    }
    __syncthreads();
    if (t < 8) {
        float s = part[0][t] + part[1][t] + part[2][t] + part[3][t];
        int gg = t >> 1, pp = t & 1;
        ws->partE[kc][(gbase + gg) * P_ + (pbase + pp)] = s;
    }
}

// ---------------- kernel 5: argmin over gallery + write outputs ----------------
__global__ void argmin_out(const WS* __restrict__ ws, float* __restrict__ out) {
    int p = threadIdx.x;
    if (p >= P_) return;
    float best = 3.4e38f;
    int bi = 0;
    for (int g = 0; g < G_; ++g) {
        double s = 0.0;
#pragma unroll
        for (int kc = 0; kc < KC; ++kc) s += (double)ws->partE[kc][g * P_ + p];
        float e = (float)(s / (double)M_);
        if (e < best) { best = e; bi = g; }
    }
    out[p] = (float)bi;
    out[P_ + p] = best;
}

extern "C" void kernel_launch(void* const* d_in, const int* in_sizes, int n_in,
                              void* d_out, int out_size, void* d_ws, size_t ws_size,
                              hipStream_t stream) {
    const float* pred = (const float*)d_in[0];   // (32, 2, 6890, 3)
    const float* gt   = (const float*)d_in[1];   // (256, 2, 6890, 3)
    float* out = (float*)d_out;                  // 64 floats: mapping(32) | min_error(32)
    WS* ws = (WS*)d_ws;                          // ~1.1 MB used

    stats_all<<<dim3(P_ + G_), dim3(256), 0, stream>>>(pred, gt, ws);
    crosscov_q<<<dim3(16 * 128 * KC), dim3(256), 0, stream>>>(pred, gt, ws);
    pair_svd<<<dim3(NPAIR / 256), dim3(256), 0, stream>>>(ws);
    pair_error_q<<<dim3(16 * 64 * KC), dim3(256), 0, stream>>>(pred, gt, ws);
    argmin_out<<<dim3(1), dim3(64), 0, stream>>>(ws, out);
}

// Round 5
// 224.469 us; speedup vs baseline: 2.0592x; 1.2642x over previous
//
#include <hip/hip_runtime.h>
#include <math.h>

#define P_ 32
#define G_ 256
#define NV 6890
#define M_ (2 * NV)          // 13780 joint points per sample
#define QUADS (M_ / 4)       // 3445 vertex-quads (exact)
#define NPAIR (P_ * G_)      // 8192

// ---------------- workspace layout ----------------
struct WS {
    float mu_p[P_][3];
    float var_p[P_];
    float mu_g[G_][3];
    float At[NPAIR][12];     // A = scale*R (9) then t (3); pair = g*32 + p
    float Kmat[NPAIR][9];    // cross-covariance (pre mean-subtraction)
    float pair_err[NPAIR];   // mean v2v error per pair
};

// ---------------- block reduction (valid on thread 0) ----------------
__device__ inline double block_reduce(double v, double* smem) {
#pragma unroll
    for (int off = 32; off > 0; off >>= 1) v += __shfl_down(v, off, 64);
    int wid  = threadIdx.x >> 6;
    int lane = threadIdx.x & 63;
    __syncthreads();
    if (lane == 0) smem[wid] = v;
    __syncthreads();
    double r = 0.0;
    if (threadIdx.x == 0) {
        int nw = blockDim.x >> 6;
        for (int w = 0; w < nw; ++w) r += smem[w];
    }
    return r;
}

// ---------------- kernel 1: stats for pred (mu,var) and gt (mu) ----------------
__global__ __launch_bounds__(256) void stats_all(const float* __restrict__ pred,
                                                 const float* __restrict__ gt, WS* ws) {
    int b = blockIdx.x;
    bool isP = (b < P_);
    const float* base = isP ? pred + (size_t)b * (M_ * 3)
                            : gt + (size_t)(b - P_) * (M_ * 3);
    double sx = 0, sy = 0, sz = 0, sq = 0;
    for (int q = threadIdx.x; q < QUADS; q += 256) {
        const float4* p4 = (const float4*)(base + 12 * (size_t)q);
        float4 a = p4[0], c = p4[1], d = p4[2];
        sx += (double)a.x + (double)a.w + (double)c.z + (double)d.y;
        sy += (double)a.y + (double)c.x + (double)c.w + (double)d.z;
        sz += (double)a.z + (double)c.y + (double)d.x + (double)d.w;
        if (isP) {
            sq += (double)a.x * a.x + (double)a.y * a.y + (double)a.z * a.z +
                  (double)a.w * a.w + (double)c.x * c.x + (double)c.y * c.y +
                  (double)c.z * c.z + (double)c.w * c.w + (double)d.x * d.x +
                  (double)d.y * d.y + (double)d.z * d.z + (double)d.w * d.w;
        }
    }
    __shared__ double smem[4];
    double rx = block_reduce(sx, smem);
    double ry = block_reduce(sy, smem);
    double rz = block_reduce(sz, smem);
    double rq = block_reduce(sq, smem);
    if (threadIdx.x == 0) {
        double mx = rx / M_, my = ry / M_, mz = rz / M_;
        if (isP) {
            ws->mu_p[b][0] = (float)mx;
            ws->mu_p[b][1] = (float)my;
            ws->mu_p[b][2] = (float)mz;
            ws->var_p[b] = (float)(rq - (mx * mx + my * my + mz * mz) * (double)M_);
        } else {
            ws->mu_g[b - P_][0] = (float)mx;
            ws->mu_g[b - P_][1] = (float)my;
            ws->mu_g[b - P_][2] = (float)mz;
        }
    }
}

// load one 4-vertex quad (x[4],y[4],z[4]) from AoS via 3 float4 loads
#define LOAD_QUAD(BASE, Q, X, Y, Z)                                     \
    {                                                                   \
        const float4* _p4 = (const float4*)((BASE) + 12 * (size_t)(Q)); \
        float4 _a = _p4[0], _c = _p4[1], _d = _p4[2];                   \
        X[0] = _a.x; X[1] = _a.w; X[2] = _c.z; X[3] = _d.y;             \
        Y[0] = _a.y; Y[1] = _c.x; Y[2] = _c.w; Y[3] = _d.z;             \
        Z[0] = _a.z; Z[1] = _c.y; Z[2] = _d.x; Z[3] = _d.w;             \
    }

// ---------------- kernel 2: register-tiled cross-covariance (4p x 4g) ----------------
// grid: 512 blocks = ptile(8) * 64 + gtile(64); XCD = blockIdx%8 = gtile%8 so each
// gt tile's re-reads stay in one XCD's L2. Thread owns 16 pairs, 4 verts/iter;
// gt quads streamed (loaded once per gg, reused across 4 pp).
__global__ __launch_bounds__(256, 2) void crosscov_r(const float* __restrict__ pred,
                                                     const float* __restrict__ gt,
                                                     WS* __restrict__ ws) {
    int bx = blockIdx.x;
    int gbase = (bx & 63) * 4;
    int pbase = (bx >> 6) * 4;
    int t = threadIdx.x;

    const float* pb[4];
    const float* gb[4];
#pragma unroll
    for (int j = 0; j < 4; ++j) {
        pb[j] = pred + (size_t)(pbase + j) * (M_ * 3);
        gb[j] = gt + (size_t)(gbase + j) * (M_ * 3);
    }

    float acc[16][9];
#pragma unroll
    for (int q = 0; q < 16; ++q)
#pragma unroll
        for (int j = 0; j < 9; ++j) acc[q][j] = 0.f;

    for (int q = t; q < QUADS; q += 256) {
        float px[4][4], py[4][4], pz[4][4];
#pragma unroll
        for (int j = 0; j < 4; ++j) LOAD_QUAD(pb[j], q, px[j], py[j], pz[j]);
#pragma unroll
        for (int gg = 0; gg < 4; ++gg) {
            float gx[4], gy[4], gz[4];
            LOAD_QUAD(gb[gg], q, gx, gy, gz);
#pragma unroll
            for (int pp = 0; pp < 4; ++pp) {
                float* a = acc[gg * 4 + pp];
#pragma unroll
                for (int k = 0; k < 4; ++k) {
                    a[0] = fmaf(px[pp][k], gx[k], a[0]);
                    a[1] = fmaf(px[pp][k], gy[k], a[1]);
                    a[2] = fmaf(px[pp][k], gz[k], a[2]);
                    a[3] = fmaf(py[pp][k], gx[k], a[3]);
                    a[4] = fmaf(py[pp][k], gy[k], a[4]);
                    a[5] = fmaf(py[pp][k], gz[k], a[5]);
                    a[6] = fmaf(pz[pp][k], gx[k], a[6]);
                    a[7] = fmaf(pz[pp][k], gy[k], a[7]);
                    a[8] = fmaf(pz[pp][k], gz[k], a[8]);
                }
            }
        }
    }

    // full-wave butterfly -> every lane holds wave total
#pragma unroll
    for (int q = 0; q < 16; ++q)
#pragma unroll
        for (int j = 0; j < 9; ++j) {
            float v = acc[q][j];
            v += __shfl_xor(v, 1);  v += __shfl_xor(v, 2);
            v += __shfl_xor(v, 4);  v += __shfl_xor(v, 8);
            v += __shfl_xor(v, 16); v += __shfl_xor(v, 32);
            acc[q][j] = v;
        }
    __shared__ float part[4][144];
    int lane = t & 63, wave = t >> 6;
    if (lane == 0) {
#pragma unroll
        for (int q = 0; q < 16; ++q)
#pragma unroll
            for (int j = 0; j < 9; ++j) part[wave][q * 9 + j] = acc[q][j];
    }
    __syncthreads();
    if (t < 144) {
        float s = part[0][t] + part[1][t] + part[2][t] + part[3][t];
        int idx = t / 9, j = t % 9;
        int gg = idx >> 2, pp = idx & 3;
        ws->Kmat[(gbase + gg) * P_ + (pbase + pp)][j] = s;
    }
}

// ---------------- kernel 3: per-pair SVD -> A = scale*R, t ----------------
__global__ __launch_bounds__(256) void pair_svd(WS* ws) {
    int pair = blockIdx.x * blockDim.x + threadIdx.x;
    if (pair >= NPAIR) return;
    int p = pair & 31;
    int g = pair >> 5;

    double K[3][3];
#pragma unroll
    for (int a = 0; a < 3; ++a)
#pragma unroll
        for (int b = 0; b < 3; ++b) K[a][b] = (double)ws->Kmat[pair][3 * a + b];
    {   // subtract M * mu_p mu_g^T
        double mp[3] = { ws->mu_p[p][0], ws->mu_p[p][1], ws->mu_p[p][2] };
        double mg[3] = { ws->mu_g[g][0], ws->mu_g[g][1], ws->mu_g[g][2] };
#pragma unroll
        for (int a = 0; a < 3; ++a)
#pragma unroll
            for (int b = 0; b < 3; ++b)
                K[a][b] -= (double)M_ * mp[a] * mg[b];
    }

    // S = K^T K (symmetric PSD)
    double S[3][3];
#pragma unroll
    for (int a = 0; a < 3; ++a)
#pragma unroll
        for (int b = 0; b < 3; ++b) {
            double acc = 0.0;
#pragma unroll
            for (int c = 0; c < 3; ++c) acc += K[c][a] * K[c][b];
            S[a][b] = acc;
        }

    // Jacobi eigendecomposition S = V Lambda V^T
    double V[3][3] = { {1, 0, 0}, {0, 1, 0}, {0, 0, 1} };
    double tr = S[0][0] + S[1][1] + S[2][2];
    double tol = 1e-30 * tr * tr + 1e-300;
    const int PP[3] = {0, 0, 1};
    const int QQ[3] = {1, 2, 2};
    for (int sweep = 0; sweep < 30; ++sweep) {
        double off = S[0][1] * S[0][1] + S[0][2] * S[0][2] + S[1][2] * S[1][2];
        if (off <= tol) break;
        for (int r3 = 0; r3 < 3; ++r3) {
            int pq = PP[r3], qq = QQ[r3];
            double apq = S[pq][qq];
            if (apq == 0.0) continue;
            double theta = (S[qq][qq] - S[pq][pq]) / (2.0 * apq);
            double tt = copysign(1.0, theta) / (fabs(theta) + sqrt(theta * theta + 1.0));
            double c = 1.0 / sqrt(tt * tt + 1.0);
            double sj = tt * c;
            for (int r = 0; r < 3; ++r) {
                double srp = S[r][pq], srq = S[r][qq];
                S[r][pq] = c * srp - sj * srq;
                S[r][qq] = sj * srp + c * srq;
            }
            for (int cc = 0; cc < 3; ++cc) {
                double spr = S[pq][cc], sqr = S[qq][cc];
                S[pq][cc] = c * spr - sj * sqr;
                S[qq][cc] = sj * spr + c * sqr;
            }
            for (int r = 0; r < 3; ++r) {
                double vrp = V[r][pq], vrq = V[r][qq];
                V[r][pq] = c * vrp - sj * vrq;
                V[r][qq] = sj * vrp + c * vrq;
            }
        }
    }

    // sort eigenpairs descending
    double lam[3] = { S[0][0], S[1][1], S[2][2] };
    int idx[3] = { 0, 1, 2 };
    if (lam[idx[0]] < lam[idx[1]]) { int tt = idx[0]; idx[0] = idx[1]; idx[1] = tt; }
    if (lam[idx[0]] < lam[idx[2]]) { int tt = idx[0]; idx[0] = idx[2]; idx[2] = tt; }
    if (lam[idx[1]] < lam[idx[2]]) { int tt = idx[1]; idx[1] = idx[2]; idx[2] = tt; }
    double Vs[3][3];
    double sv[3];
#pragma unroll
    for (int i = 0; i < 3; ++i) {
        double l = lam[idx[i]];
        sv[i] = sqrt(l > 0.0 ? l : 0.0);
        for (int r = 0; r < 3; ++r) Vs[r][i] = V[r][idx[i]];
    }

    // U columns: u_i = K v_i / s_i
    double U[3][3];
#pragma unroll
    for (int i = 0; i < 3; ++i) {
        double kx = K[0][0] * Vs[0][i] + K[0][1] * Vs[1][i] + K[0][2] * Vs[2][i];
        double ky = K[1][0] * Vs[0][i] + K[1][1] * Vs[1][i] + K[1][2] * Vs[2][i];
        double kz = K[2][0] * Vs[0][i] + K[2][1] * Vs[1][i] + K[2][2] * Vs[2][i];
        double inv = (sv[i] > 1e-12 * sv[0] && sv[i] > 0.0) ? 1.0 / sv[i] : 0.0;
        U[0][i] = kx * inv; U[1][i] = ky * inv; U[2][i] = kz * inv;
    }
    if (sv[2] <= 1e-12 * sv[0] || sv[0] == 0.0) {
        U[0][2] = U[1][0] * U[2][1] - U[2][0] * U[1][1];
        U[1][2] = U[2][0] * U[0][1] - U[0][0] * U[2][1];
        U[2][2] = U[0][0] * U[1][1] - U[1][0] * U[0][1];
    }

    double detK = K[0][0] * (K[1][1] * K[2][2] - K[1][2] * K[2][1])
                - K[0][1] * (K[1][0] * K[2][2] - K[1][2] * K[2][0])
                + K[0][2] * (K[1][0] * K[2][1] - K[1][1] * K[2][0]);
    double d = (detK >= 0.0) ? 1.0 : -1.0;

    double varp = (double)ws->var_p[p];
    double scale = (sv[0] + sv[1] + d * sv[2]) / varp;

    float A[9];
#pragma unroll
    for (int a = 0; a < 3; ++a)
#pragma unroll
        for (int b = 0; b < 3; ++b) {
            double r = Vs[a][0] * U[b][0] + Vs[a][1] * U[b][1] + d * Vs[a][2] * U[b][2];
            A[3 * a + b] = (float)(scale * r);
        }
    double mp[3] = { ws->mu_p[p][0], ws->mu_p[p][1], ws->mu_p[p][2] };
    double mg[3] = { ws->mu_g[g][0], ws->mu_g[g][1], ws->mu_g[g][2] };
    float tvec[3];
#pragma unroll
    for (int a = 0; a < 3; ++a)
        tvec[a] = (float)(mg[a] - ((double)A[3 * a + 0] * mp[0] + (double)A[3 * a + 1] * mp[1] +
                                   (double)A[3 * a + 2] * mp[2]));

#pragma unroll
    for (int j = 0; j < 9; ++j) ws->At[pair][j] = A[j];
#pragma unroll
    for (int j = 0; j < 3; ++j) ws->At[pair][9 + j] = tvec[j];
}

// ---------------- kernel 4: register-tiled v2v error (2p x 4g) ----------------
// grid: 1024 blocks = ptile(16) * 64 + gtile(64); XCD = gtile%8. A-matrices are
// block-uniform -> scalar loads. gt quads streamed across the 2 pp.
__global__ __launch_bounds__(256, 3) void pair_error_r(const float* __restrict__ pred,
                                                       const float* __restrict__ gt,
                                                       WS* __restrict__ ws) {
    int bx = blockIdx.x;
    int gbase = (bx & 63) * 4;
    int pbase = (bx >> 6) * 2;
    int t = threadIdx.x;

    float A[8][12];
#pragma unroll
    for (int gg = 0; gg < 4; ++gg)
#pragma unroll
        for (int pp = 0; pp < 2; ++pp) {
            int pair = (gbase + gg) * P_ + (pbase + pp);
#pragma unroll
            for (int j = 0; j < 12; ++j) A[gg * 2 + pp][j] = ws->At[pair][j];
        }

    const float* pb0 = pred + (size_t)pbase * (M_ * 3);
    const float* pb1 = pred + (size_t)(pbase + 1) * (M_ * 3);
    const float* gb[4];
#pragma unroll
    for (int j = 0; j < 4; ++j) gb[j] = gt + (size_t)(gbase + j) * (M_ * 3);

    float acc[8];
#pragma unroll
    for (int q = 0; q < 8; ++q) acc[q] = 0.f;

    for (int q = t; q < QUADS; q += 256) {
        float px[2][4], py[2][4], pz[2][4];
        LOAD_QUAD(pb0, q, px[0], py[0], pz[0]);
        LOAD_QUAD(pb1, q, px[1], py[1], pz[1]);
#pragma unroll
        for (int gg = 0; gg < 4; ++gg) {
            float gx[4], gy[4], gz[4];
            LOAD_QUAD(gb[gg], q, gx, gy, gz);
#pragma unroll
            for (int pp = 0; pp < 2; ++pp) {
                const float* a = A[gg * 2 + pp];
                float s = 0.f;
#pragma unroll
                for (int k = 0; k < 4; ++k) {
                    float dx = fmaf(a[0], px[pp][k], fmaf(a[1], py[pp][k], fmaf(a[2], pz[pp][k], a[9])))  - gx[k];
                    float dy = fmaf(a[3], px[pp][k], fmaf(a[4], py[pp][k], fmaf(a[5], pz[pp][k], a[10]))) - gy[k];
                    float dz = fmaf(a[6], px[pp][k], fmaf(a[7], py[pp][k], fmaf(a[8], pz[pp][k], a[11]))) - gz[k];
                    s += __builtin_amdgcn_sqrtf(fmaf(dx, dx, fmaf(dy, dy, dz * dz)));
                }
                acc[gg * 2 + pp] += s;
            }
        }
    }

#pragma unroll
    for (int q = 0; q < 8; ++q) {
        float v = acc[q];
        v += __shfl_xor(v, 1);  v += __shfl_xor(v, 2);
        v += __shfl_xor(v, 4);  v += __shfl_xor(v, 8);
        v += __shfl_xor(v, 16); v += __shfl_xor(v, 32);
        acc[q] = v;
    }
    __shared__ float part[4][8];
    int lane = t & 63, wave = t >> 6;
    if (lane == 0) {
#pragma unroll
        for (int q = 0; q < 8; ++q) part[wave][q] = acc[q];
    }
    __syncthreads();
    if (t < 8) {
        float s = part[0][t] + part[1][t] + part[2][t] + part[3][t];
        int gg = t >> 1, pp = t & 1;
        ws->pair_err[(gbase + gg) * P_ + (pbase + pp)] = s / (float)M_;
    }
}

// ---------------- kernel 5: argmin over gallery + write outputs ----------------
// 256 threads: p = t&31, slice = t>>5 scans g = slice, slice+8, ... (first-index ties)
__global__ void argmin_out(const WS* __restrict__ ws, float* __restrict__ out) {
    __shared__ float be[8][32];
    __shared__ int   bg[8][32];
    int t = threadIdx.x;
    int p = t & 31, slice = t >> 5;
    float best = 3.4e38f;
    int bi = G_;
    for (int g = slice; g < G_; g += 8) {
        float e = ws->pair_err[g * P_ + p];
        if (e < best) { best = e; bi = g; }
    }
    be[slice][p] = best;
    bg[slice][p] = bi;
    __syncthreads();
    if (t < P_) {
        float b0 = be[0][t];
        int   i0 = bg[0][t];
        for (int s = 1; s < 8; ++s) {
            float e = be[s][t];
            int   i = bg[s][t];
            if (e < b0 || (e == b0 && i < i0)) { b0 = e; i0 = i; }
        }
        out[t] = (float)i0;
        out[P_ + t] = b0;
    }
}

extern "C" void kernel_launch(void* const* d_in, const int* in_sizes, int n_in,
                              void* d_out, int out_size, void* d_ws, size_t ws_size,
                              hipStream_t stream) {
    const float* pred = (const float*)d_in[0];   // (32, 2, 6890, 3)
    const float* gt   = (const float*)d_in[1];   // (256, 2, 6890, 3)
    float* out = (float*)d_out;                  // 64 floats: mapping(32) | min_error(32)
    WS* ws = (WS*)d_ws;                          // ~0.8 MB used

    stats_all<<<dim3(P_ + G_), dim3(256), 0, stream>>>(pred, gt, ws);
    crosscov_r<<<dim3(8 * 64), dim3(256), 0, stream>>>(pred, gt, ws);
    pair_svd<<<dim3(NPAIR / 256), dim3(256), 0, stream>>>(ws);
    pair_error_r<<<dim3(16 * 64), dim3(256), 0, stream>>>(pred, gt, ws);
    argmin_out<<<dim3(1), dim3(256), 0, stream>>>(ws, out);
}

// Round 6
// 209.804 us; speedup vs baseline: 2.2032x; 1.0699x over previous
//
#include <hip/hip_runtime.h>
#include <math.h>

#define P_ 32
#define G_ 256
#define NV 6890
#define M_ (2 * NV)          // 13780 joint points per sample
#define QUADS (M_ / 4)       // 3445 vertex-quads (exact)
#define NPAIR (P_ * G_)      // 8192
#define NB_CC 512            // crosscov blocks; stats blocks appended after

typedef float v2f __attribute__((ext_vector_type(2)));
__device__ inline v2f v2(float a, float b) { v2f r; r.x = a; r.y = b; return r; }
__device__ inline v2f vsplat(float a) { v2f r; r.x = a; r.y = a; return r; }
__device__ inline v2f vfma(v2f a, v2f b, v2f c) { return __builtin_elementwise_fma(a, b, c); }

// ---------------- workspace layout ----------------
struct WS {
    float mu_p[P_][3];
    float var_p[P_];
    float mu_g[G_][3];
    float At[NPAIR][12];     // A = scale*R (9) then t (3); pair = g*32 + p
    float Kmat[NPAIR][9];    // cross-covariance (pre mean-subtraction)
    float pair_err[NPAIR];   // mean v2v error per pair
};

// ---------------- block reduction (valid on thread 0) ----------------
__device__ inline double block_reduce(double v, double* smem) {
#pragma unroll
    for (int off = 32; off > 0; off >>= 1) v += __shfl_down(v, off, 64);
    int wid  = threadIdx.x >> 6;
    int lane = threadIdx.x & 63;
    __syncthreads();
    if (lane == 0) smem[wid] = v;
    __syncthreads();
    double r = 0.0;
    if (threadIdx.x == 0) {
        int nw = blockDim.x >> 6;
        for (int w = 0; w < nw; ++w) r += smem[w];
    }
    return r;
}

// ---------------- kernel 1: packed crosscov (4p x 4g) + fused stats ----------------
// blocks 0..511: ptile(8)*64 + gtile(64), XCD = gtile%8 keeps gt re-reads L2-local.
// blocks 512..799: per-sample stats (0..31 pred mu/var, 32..287 gt mu).
__global__ __launch_bounds__(256, 2) void crosscov_p(const float* __restrict__ pred,
                                                     const float* __restrict__ gt,
                                                     WS* __restrict__ ws) {
    int bx = blockIdx.x;
    int t = threadIdx.x;

    if (bx >= NB_CC) {
        // ---- stats path ----
        int b = bx - NB_CC;
        bool isP = (b < P_);
        const float* base = isP ? pred + (size_t)b * (M_ * 3)
                                : gt + (size_t)(b - P_) * (M_ * 3);
        double sx = 0, sy = 0, sz = 0, sq = 0;
        for (int q = t; q < QUADS; q += 256) {
            const float4* p4 = (const float4*)(base + 12 * (size_t)q);
            float4 a = p4[0], c = p4[1], d = p4[2];
            sx += (double)a.x + (double)a.w + (double)c.z + (double)d.y;
            sy += (double)a.y + (double)c.x + (double)c.w + (double)d.z;
            sz += (double)a.z + (double)c.y + (double)d.x + (double)d.w;
            if (isP) {
                sq += (double)a.x * a.x + (double)a.y * a.y + (double)a.z * a.z +
                      (double)a.w * a.w + (double)c.x * c.x + (double)c.y * c.y +
                      (double)c.z * c.z + (double)c.w * c.w + (double)d.x * d.x +
                      (double)d.y * d.y + (double)d.z * d.z + (double)d.w * d.w;
            }
        }
        __shared__ double smem[4];
        double rx = block_reduce(sx, smem);
        double ry = block_reduce(sy, smem);
        double rz = block_reduce(sz, smem);
        double rq = block_reduce(sq, smem);
        if (t == 0) {
            double mx = rx / M_, my = ry / M_, mz = rz / M_;
            if (isP) {
                ws->mu_p[b][0] = (float)mx;
                ws->mu_p[b][1] = (float)my;
                ws->mu_p[b][2] = (float)mz;
                ws->var_p[b] = (float)(rq - (mx * mx + my * my + mz * mz) * (double)M_);
            } else {
                ws->mu_g[b - P_][0] = (float)mx;
                ws->mu_g[b - P_][1] = (float)my;
                ws->mu_g[b - P_][2] = (float)mz;
            }
        }
        return;
    }

    // ---- crosscov path ----
    int gbase = (bx & 63) * 4;
    int pbase = (bx >> 6) * 4;
    const float* pb[4];
    const float* gb[4];
#pragma unroll
    for (int j = 0; j < 4; ++j) {
        pb[j] = pred + (size_t)(pbase + j) * (M_ * 3);
        gb[j] = gt + (size_t)(gbase + j) * (M_ * 3);
    }

    // acc per pair: (K0,K1) (K3,K4) (K6,K7) packed; (K2,K5) packed; K8 scalar
    v2f a01[16], a34[16], a67[16], a25[16];
    float a8[16];
#pragma unroll
    for (int i = 0; i < 16; ++i) {
        a01[i] = vsplat(0.f); a34[i] = vsplat(0.f);
        a67[i] = vsplat(0.f); a25[i] = vsplat(0.f);
        a8[i] = 0.f;
    }

    for (int q = t; q < QUADS; q += 256) {
        float4 P[4][3];
#pragma unroll
        for (int j = 0; j < 4; ++j) {
            const float4* p4 = (const float4*)(pb[j] + 12 * (size_t)q);
            P[j][0] = p4[0]; P[j][1] = p4[1]; P[j][2] = p4[2];
        }
#pragma unroll
        for (int gg = 0; gg < 4; ++gg) {
            const float4* g4 = (const float4*)(gb[gg] + 12 * (size_t)q);
            float4 Ga = g4[0], Gc = g4[1], Gd = g4[2];
            v2f gxy0 = v2(Ga.x, Ga.y), gxy1 = v2(Ga.w, Gc.x);
            v2f gxy2 = v2(Gc.z, Gc.w), gxy3 = v2(Gd.y, Gd.z);
            float gz0 = Ga.z, gz1 = Gc.y, gz2 = Gd.x, gz3 = Gd.w;
#pragma unroll
            for (int pp = 0; pp < 4; ++pp) {
                int i = gg * 4 + pp;
                float4 Pa = P[pp][0], Pc = P[pp][1], Pd = P[pp][2];
                // vertex 0: (x,y,z) = (Pa.x, Pa.y, Pa.z)
                a01[i] = vfma(vsplat(Pa.x), gxy0, a01[i]);
                a34[i] = vfma(vsplat(Pa.y), gxy0, a34[i]);
                a67[i] = vfma(vsplat(Pa.z), gxy0, a67[i]);
                a25[i] = vfma(v2(Pa.x, Pa.y), vsplat(gz0), a25[i]);
                a8[i]  = fmaf(Pa.z, gz0, a8[i]);
                // vertex 1: (Pa.w, Pc.x, Pc.y)
                a01[i] = vfma(vsplat(Pa.w), gxy1, a01[i]);
                a34[i] = vfma(vsplat(Pc.x), gxy1, a34[i]);
                a67[i] = vfma(vsplat(Pc.y), gxy1, a67[i]);
                a25[i] = vfma(v2(Pa.w, Pc.x), vsplat(gz1), a25[i]);
                a8[i]  = fmaf(Pc.y, gz1, a8[i]);
                // vertex 2: (Pc.z, Pc.w, Pd.x)
                a01[i] = vfma(vsplat(Pc.z), gxy2, a01[i]);
                a34[i] = vfma(vsplat(Pc.w), gxy2, a34[i]);
                a67[i] = vfma(vsplat(Pd.x), gxy2, a67[i]);
                a25[i] = vfma(v2(Pc.z, Pc.w), vsplat(gz2), a25[i]);
                a8[i]  = fmaf(Pd.x, gz2, a8[i]);
                // vertex 3: (Pd.y, Pd.z, Pd.w)
                a01[i] = vfma(vsplat(Pd.y), gxy3, a01[i]);
                a34[i] = vfma(vsplat(Pd.z), gxy3, a34[i]);
                a67[i] = vfma(vsplat(Pd.w), gxy3, a67[i]);
                a25[i] = vfma(v2(Pd.y, Pd.z), vsplat(gz3), a25[i]);
                a8[i]  = fmaf(Pd.w, gz3, a8[i]);
            }
        }
    }

    // unpack to K[16][9]
    float K[16][9];
#pragma unroll
    for (int i = 0; i < 16; ++i) {
        K[i][0] = a01[i].x; K[i][1] = a01[i].y; K[i][2] = a25[i].x;
        K[i][3] = a34[i].x; K[i][4] = a34[i].y; K[i][5] = a25[i].y;
        K[i][6] = a67[i].x; K[i][7] = a67[i].y; K[i][8] = a8[i];
    }

    // full-wave butterfly -> every lane holds wave total
#pragma unroll
    for (int i = 0; i < 16; ++i)
#pragma unroll
        for (int j = 0; j < 9; ++j) {
            float v = K[i][j];
            v += __shfl_xor(v, 1);  v += __shfl_xor(v, 2);
            v += __shfl_xor(v, 4);  v += __shfl_xor(v, 8);
            v += __shfl_xor(v, 16); v += __shfl_xor(v, 32);
            K[i][j] = v;
        }
    __shared__ float part[4][144];
    int lane = t & 63, wave = t >> 6;
    if (lane == 0) {
#pragma unroll
        for (int i = 0; i < 16; ++i)
#pragma unroll
            for (int j = 0; j < 9; ++j) part[wave][i * 9 + j] = K[i][j];
    }
    __syncthreads();
    if (t < 144) {
        float s = part[0][t] + part[1][t] + part[2][t] + part[3][t];
        int idx = t / 9, j = t % 9;
        int gg = idx >> 2, pp = idx & 3;
        ws->Kmat[(gbase + gg) * P_ + (pbase + pp)][j] = s;
    }
}

// ---------------- kernel 2: per-pair SVD -> A = scale*R, t ----------------
__global__ __launch_bounds__(256) void pair_svd(WS* ws) {
    int pair = blockIdx.x * blockDim.x + threadIdx.x;
    if (pair >= NPAIR) return;
    int p = pair & 31;
    int g = pair >> 5;

    double K[3][3];
#pragma unroll
    for (int a = 0; a < 3; ++a)
#pragma unroll
        for (int b = 0; b < 3; ++b) K[a][b] = (double)ws->Kmat[pair][3 * a + b];
    {   // subtract M * mu_p mu_g^T
        double mp[3] = { ws->mu_p[p][0], ws->mu_p[p][1], ws->mu_p[p][2] };
        double mg[3] = { ws->mu_g[g][0], ws->mu_g[g][1], ws->mu_g[g][2] };
#pragma unroll
        for (int a = 0; a < 3; ++a)
#pragma unroll
            for (int b = 0; b < 3; ++b)
                K[a][b] -= (double)M_ * mp[a] * mg[b];
    }

    // S = K^T K (symmetric PSD)
    double S[3][3];
#pragma unroll
    for (int a = 0; a < 3; ++a)
#pragma unroll
        for (int b = 0; b < 3; ++b) {
            double acc = 0.0;
#pragma unroll
            for (int c = 0; c < 3; ++c) acc += K[c][a] * K[c][b];
            S[a][b] = acc;
        }

    // Jacobi eigendecomposition S = V Lambda V^T
    double V[3][3] = { {1, 0, 0}, {0, 1, 0}, {0, 0, 1} };
    double tr = S[0][0] + S[1][1] + S[2][2];
    double tol = 1e-30 * tr * tr + 1e-300;
    const int PP[3] = {0, 0, 1};
    const int QQ[3] = {1, 2, 2};
    for (int sweep = 0; sweep < 30; ++sweep) {
        double off = S[0][1] * S[0][1] + S[0][2] * S[0][2] + S[1][2] * S[1][2];
        if (off <= tol) break;
        for (int r3 = 0; r3 < 3; ++r3) {
            int pq = PP[r3], qq = QQ[r3];
            double apq = S[pq][qq];
            if (apq == 0.0) continue;
            double theta = (S[qq][qq] - S[pq][pq]) / (2.0 * apq);
            double tt = copysign(1.0, theta) / (fabs(theta) + sqrt(theta * theta + 1.0));
            double c = 1.0 / sqrt(tt * tt + 1.0);
            double sj = tt * c;
            for (int r = 0; r < 3; ++r) {
                double srp = S[r][pq], srq = S[r][qq];
                S[r][pq] = c * srp - sj * srq;
                S[r][qq] = sj * srp + c * srq;
            }
            for (int cc = 0; cc < 3; ++cc) {
                double spr = S[pq][cc], sqr = S[qq][cc];
                S[pq][cc] = c * spr - sj * sqr;
                S[qq][cc] = sj * spr + c * sqr;
            }
            for (int r = 0; r < 3; ++r) {
                double vrp = V[r][pq], vrq = V[r][qq];
                V[r][pq] = c * vrp - sj * vrq;
                V[r][qq] = sj * vrp + c * vrq;
            }
        }
    }

    // sort eigenpairs descending
    double lam[3] = { S[0][0], S[1][1], S[2][2] };
    int idx[3] = { 0, 1, 2 };
    if (lam[idx[0]] < lam[idx[1]]) { int tt = idx[0]; idx[0] = idx[1]; idx[1] = tt; }
    if (lam[idx[0]] < lam[idx[2]]) { int tt = idx[0]; idx[0] = idx[2]; idx[2] = tt; }
    if (lam[idx[1]] < lam[idx[2]]) { int tt = idx[1]; idx[1] = idx[2]; idx[2] = tt; }
    double Vs[3][3];
    double sv[3];
#pragma unroll
    for (int i = 0; i < 3; ++i) {
        double l = lam[idx[i]];
        sv[i] = sqrt(l > 0.0 ? l : 0.0);
        for (int r = 0; r < 3; ++r) Vs[r][i] = V[r][idx[i]];
    }

    // U columns: u_i = K v_i / s_i
    double U[3][3];
#pragma unroll
    for (int i = 0; i < 3; ++i) {
        double kx = K[0][0] * Vs[0][i] + K[0][1] * Vs[1][i] + K[0][2] * Vs[2][i];
        double ky = K[1][0] * Vs[0][i] + K[1][1] * Vs[1][i] + K[1][2] * Vs[2][i];
        double kz = K[2][0] * Vs[0][i] + K[2][1] * Vs[1][i] + K[2][2] * Vs[2][i];
        double inv = (sv[i] > 1e-12 * sv[0] && sv[i] > 0.0) ? 1.0 / sv[i] : 0.0;
        U[0][i] = kx * inv; U[1][i] = ky * inv; U[2][i] = kz * inv;
    }
    if (sv[2] <= 1e-12 * sv[0] || sv[0] == 0.0) {
        U[0][2] = U[1][0] * U[2][1] - U[2][0] * U[1][1];
        U[1][2] = U[2][0] * U[0][1] - U[0][0] * U[2][1];
        U[2][2] = U[0][0] * U[1][1] - U[1][0] * U[0][1];
    }

    double detK = K[0][0] * (K[1][1] * K[2][2] - K[1][2] * K[2][1])
                - K[0][1] * (K[1][0] * K[2][2] - K[1][2] * K[2][0])
                + K[0][2] * (K[1][0] * K[2][1] - K[1][1] * K[2][0]);
    double d = (detK >= 0.0) ? 1.0 : -1.0;

    double varp = (double)ws->var_p[p];
    double scale = (sv[0] + sv[1] + d * sv[2]) / varp;

    float A[9];
#pragma unroll
    for (int a = 0; a < 3; ++a)
#pragma unroll
        for (int b = 0; b < 3; ++b) {
            double r = Vs[a][0] * U[b][0] + Vs[a][1] * U[b][1] + d * Vs[a][2] * U[b][2];
            A[3 * a + b] = (float)(scale * r);
        }
    double mp[3] = { ws->mu_p[p][0], ws->mu_p[p][1], ws->mu_p[p][2] };
    double mg[3] = { ws->mu_g[g][0], ws->mu_g[g][1], ws->mu_g[g][2] };
    float tvec[3];
#pragma unroll
    for (int a = 0; a < 3; ++a)
        tvec[a] = (float)(mg[a] - ((double)A[3 * a + 0] * mp[0] + (double)A[3 * a + 1] * mp[1] +
                                   (double)A[3 * a + 2] * mp[2]));

#pragma unroll
    for (int j = 0; j < 9; ++j) ws->At[pair][j] = A[j];
#pragma unroll
    for (int j = 0; j < 3; ++j) ws->At[pair][9 + j] = tvec[j];
}

// ---------------- kernel 3: packed v2v error (2p x 4g) ----------------
// grid: 1024 = ptile(16)*64 + gtile(64); XCD = gtile%8. A rows 0,1 packed:
// dxy via v_pk_fma, dz scalar. acc scalar f32 per pair.
__global__ __launch_bounds__(256, 3) void pair_error_p(const float* __restrict__ pred,
                                                       const float* __restrict__ gt,
                                                       WS* __restrict__ ws) {
    int bx = blockIdx.x;
    int gbase = (bx & 63) * 4;
    int pbase = (bx >> 6) * 2;
    int t = threadIdx.x;

    v2f a03[8], a14[8], a25v[8], t01[8];
    float a6[8], a7[8], a8v[8], t2[8];
#pragma unroll
    for (int gg = 0; gg < 4; ++gg)
#pragma unroll
        for (int pp = 0; pp < 2; ++pp) {
            int i = gg * 2 + pp;
            const float* At = ws->At[(gbase + gg) * P_ + (pbase + pp)];
            a03[i] = v2(At[0], At[3]);
            a14[i] = v2(At[1], At[4]);
            a25v[i] = v2(At[2], At[5]);
            t01[i] = v2(At[9], At[10]);
            a6[i] = At[6]; a7[i] = At[7]; a8v[i] = At[8]; t2[i] = At[11];
        }

    const float* pb0 = pred + (size_t)pbase * (M_ * 3);
    const float* pb1 = pred + (size_t)(pbase + 1) * (M_ * 3);
    const float* gb[4];
#pragma unroll
    for (int j = 0; j < 4; ++j) gb[j] = gt + (size_t)(gbase + j) * (M_ * 3);

    float acc[8];
#pragma unroll
    for (int i = 0; i < 8; ++i) acc[i] = 0.f;

    for (int q = t; q < QUADS; q += 256) {
        float4 P[2][3];
        {
            const float4* p4 = (const float4*)(pb0 + 12 * (size_t)q);
            P[0][0] = p4[0]; P[0][1] = p4[1]; P[0][2] = p4[2];
            p4 = (const float4*)(pb1 + 12 * (size_t)q);
            P[1][0] = p4[0]; P[1][1] = p4[1]; P[1][2] = p4[2];
        }
#pragma unroll
        for (int gg = 0; gg < 4; ++gg) {
            const float4* g4 = (const float4*)(gb[gg] + 12 * (size_t)q);
            float4 Ga = g4[0], Gc = g4[1], Gd = g4[2];
            v2f gxy[4] = { v2(Ga.x, Ga.y), v2(Ga.w, Gc.x), v2(Gc.z, Gc.w), v2(Gd.y, Gd.z) };
            float gz[4] = { Ga.z, Gc.y, Gd.x, Gd.w };
#pragma unroll
            for (int pp = 0; pp < 2; ++pp) {
                int i = gg * 2 + pp;
                float4 Pa = P[pp][0], Pc = P[pp][1], Pd = P[pp][2];
                float x[4] = { Pa.x, Pa.w, Pc.z, Pd.y };
                float y[4] = { Pa.y, Pc.x, Pc.w, Pd.z };
                float z[4] = { Pa.z, Pc.y, Pd.x, Pd.w };
                float s = 0.f;
#pragma unroll
                for (int k = 0; k < 4; ++k) {
                    v2f dd = vfma(a03[i], vsplat(x[k]),
                             vfma(a14[i], vsplat(y[k]),
                             vfma(a25v[i], vsplat(z[k]), t01[i])));
                    dd = dd - gxy[k];
                    float dz = fmaf(a6[i], x[k], fmaf(a7[i], y[k], fmaf(a8v[i], z[k], t2[i]))) - gz[k];
                    v2f m = dd * dd;
                    s += __builtin_amdgcn_sqrtf(fmaf(dz, dz, m.x + m.y));
                }
                acc[i] += s;
            }
        }
    }

#pragma unroll
    for (int i = 0; i < 8; ++i) {
        float v = acc[i];
        v += __shfl_xor(v, 1);  v += __shfl_xor(v, 2);
        v += __shfl_xor(v, 4);  v += __shfl_xor(v, 8);
        v += __shfl_xor(v, 16); v += __shfl_xor(v, 32);
        acc[i] = v;
    }
    __shared__ float part[4][8];
    int lane = t & 63, wave = t >> 6;
    if (lane == 0) {
#pragma unroll
        for (int i = 0; i < 8; ++i) part[wave][i] = acc[i];
    }
    __syncthreads();
    if (t < 8) {
        float s = part[0][t] + part[1][t] + part[2][t] + part[3][t];
        int gg = t >> 1, pp = t & 1;
        ws->pair_err[(gbase + gg) * P_ + (pbase + pp)] = s / (float)M_;
    }
}

// ---------------- kernel 4: argmin over gallery + write outputs ----------------
__global__ void argmin_out(const WS* __restrict__ ws, float* __restrict__ out) {
    __shared__ float be[8][32];
    __shared__ int   bg[8][32];
    int t = threadIdx.x;
    int p = t & 31, slice = t >> 5;
    float best = 3.4e38f;
    int bi = G_;
    for (int g = slice; g < G_; g += 8) {
        float e = ws->pair_err[g * P_ + p];
        if (e < best) { best = e; bi = g; }
    }
    be[slice][p] = best;
    bg[slice][p] = bi;
    __syncthreads();
    if (t < P_) {
        float b0 = be[0][t];
        int   i0 = bg[0][t];
        for (int s = 1; s < 8; ++s) {
            float e = be[s][t];
            int   i = bg[s][t];
            if (e < b0 || (e == b0 && i < i0)) { b0 = e; i0 = i; }
        }
        out[t] = (float)i0;
        out[P_ + t] = b0;
    }
}

extern "C" void kernel_launch(void* const* d_in, const int* in_sizes, int n_in,
                              void* d_out, int out_size, void* d_ws, size_t ws_size,
                              hipStream_t stream) {
    const float* pred = (const float*)d_in[0];   // (32, 2, 6890, 3)
    const float* gt   = (const float*)d_in[1];   // (256, 2, 6890, 3)
    float* out = (float*)d_out;                  // 64 floats: mapping(32) | min_error(32)
    WS* ws = (WS*)d_ws;                          // ~0.8 MB used

    crosscov_p<<<dim3(NB_CC + P_ + G_), dim3(256), 0, stream>>>(pred, gt, ws);
    pair_svd<<<dim3(NPAIR / 256), dim3(256), 0, stream>>>(ws);
    pair_error_p<<<dim3(16 * 64), dim3(256), 0, stream>>>(pred, gt, ws);
    argmin_out<<<dim3(1), dim3(256), 0, stream>>>(ws, out);
}